// Round 1
// baseline (4568.526 us; speedup 1.0000x reference)
//
#include <hip/hip_runtime.h>
#include <hip/hip_bf16.h>

#define NN 100000      // nodes
#define NE 1600000     // edges
#define NP 100000      // pos/neg label edges
// EMB=64, HID=128, OUT=64

// ---------------- degree ----------------
__global__ void k_deg(const int* __restrict__ ei, int* __restrict__ deg) {
    int e = blockIdx.x * blockDim.x + threadIdx.x;
    if (e < NE) atomicAdd(&deg[ei[NE + e]], 1);
}

__global__ void k_dinv(const int* __restrict__ deg, float* __restrict__ dinv) {
    int i = blockIdx.x * blockDim.x + threadIdx.x;
    if (i < NN) dinv[i] = rsqrtf((float)deg[i] + 1.0f);
}

// ---------------- self-loop init: agg = x * dinv^2 ----------------
// 64-feature version (16 float4 per row)
__global__ void k_selfE(const float4* __restrict__ x4, const float* __restrict__ dinv,
                        float4* __restrict__ agg4) {
    int t = blockIdx.x * blockDim.x + threadIdx.x;
    if (t >= NN * 16) return;
    int i = t >> 4;
    float s = dinv[i]; s *= s;
    float4 v = x4[t];
    v.x *= s; v.y *= s; v.z *= s; v.w *= s;
    agg4[t] = v;
}

// 128-feature version (32 float4 per row)
__global__ void k_selfH(const float4* __restrict__ x4, const float* __restrict__ dinv,
                        float4* __restrict__ agg4) {
    int t = blockIdx.x * blockDim.x + threadIdx.x;
    if (t >= NN * 32) return;
    int i = t >> 5;
    float s = dinv[i]; s *= s;
    float4 v = x4[t];
    v.x *= s; v.y *= s; v.z *= s; v.w *= s;
    agg4[t] = v;
}

// ---------------- edge scatter: agg[dst] += x[src]*dinv[src]*dinv[dst] ----------------
// 64 features: one edge per 16 lanes
__global__ void k_edgeE(const int* __restrict__ ei, const float4* __restrict__ x4,
                        const float* __restrict__ dinv, float* __restrict__ agg) {
    int t = blockIdx.x * blockDim.x + threadIdx.x;
    if (t >= NE * 16) return;
    int e = t >> 4, q = t & 15;
    int s = ei[e], d = ei[NE + e];
    float w = dinv[s] * dinv[d];
    float4 v = x4[(size_t)s * 16 + q];
    float* base = agg + (size_t)d * 64 + q * 4;
    atomicAdd(base + 0, v.x * w);
    atomicAdd(base + 1, v.y * w);
    atomicAdd(base + 2, v.z * w);
    atomicAdd(base + 3, v.w * w);
}

// 128 features: one edge per 32 lanes
__global__ void k_edgeH(const int* __restrict__ ei, const float4* __restrict__ x4,
                        const float* __restrict__ dinv, float* __restrict__ agg) {
    int t = blockIdx.x * blockDim.x + threadIdx.x;
    if (t >= NE * 32) return;
    int e = t >> 5, q = t & 31;
    int s = ei[e], d = ei[NE + e];
    float w = dinv[s] * dinv[d];
    float4 v = x4[(size_t)s * 32 + q];
    float* base = agg + (size_t)d * 128 + q * 4;
    atomicAdd(base + 0, v.x * w);
    atomicAdd(base + 1, v.y * w);
    atomicAdd(base + 2, v.z * w);
    atomicAdd(base + 3, v.w * w);
}

// ---------------- h = relu(aggE @ W1 + b1), [N,64]x[64,128] ----------------
// 256 threads, 16 rows/block (2 rows per iteration), W1 (32KB) in LDS.
__global__ __launch_bounds__(256) void k_h(const float* __restrict__ aggE,
                                           const float* __restrict__ W1,
                                           const float* __restrict__ b1,
                                           float* __restrict__ h) {
    __shared__ float w[64 * 128];
    __shared__ float rows[2][64];
    int t = threadIdx.x;
    for (int k = t; k < 64 * 128; k += 256) w[k] = W1[k];
    __syncthreads();
    int rsel = t >> 7, j = t & 127;
    float bias = b1[j];
    int base = blockIdx.x * 16;
    for (int r0 = 0; r0 < 16; r0 += 2) {
        if (t < 128) rows[t >> 6][t & 63] = aggE[(size_t)(base + r0 + (t >> 6)) * 64 + (t & 63)];
        __syncthreads();
        float acc = bias;
#pragma unroll
        for (int k = 0; k < 64; ++k) acc = fmaf(rows[rsel][k], w[k * 128 + j], acc);
        h[(size_t)(base + r0 + rsel) * 128 + j] = fmaxf(acc, 0.0f);
        __syncthreads();
    }
}

// ---------------- mu/logstd = aggH @ {W_mu,W_ls} + b, [N,128]x[128,64] ----------------
// 256 threads, 16 rows/block (2 rows/iter); both weights (64KB) in LDS.
__global__ __launch_bounds__(256) void k_out(const float* __restrict__ aggH,
                                             const float* __restrict__ Wmu,
                                             const float* __restrict__ bmu,
                                             const float* __restrict__ Wls,
                                             const float* __restrict__ bls,
                                             float* __restrict__ out) {
    __shared__ float w[2][128 * 64];
    __shared__ float rows[2][128];
    int t = threadIdx.x;
    for (int k = t; k < 128 * 64; k += 256) { w[0][k] = Wmu[k]; w[1][k] = Wls[k]; }
    __syncthreads();
    int rsel = t >> 7;          // which of the 2 rows this iteration
    int u = t & 127;
    int which = u >> 6;         // 0 = mu, 1 = logstd  (wave-uniform)
    int j = u & 63;
    float bias = which ? bls[j] : bmu[j];
    int base = blockIdx.x * 16;
    for (int r0 = 0; r0 < 16; r0 += 2) {
        rows[t >> 7][t & 127] = aggH[(size_t)(base + r0 + (t >> 7)) * 128 + (t & 127)];
        __syncthreads();
        int row = base + r0 + rsel;
        float acc = bias;
#pragma unroll
        for (int k = 0; k < 128; ++k) acc = fmaf(rows[rsel][k], w[which][k * 64 + j], acc);
        if (which == 0) out[(size_t)row * 64 + j] = acc;
        else            out[(size_t)NN * 64 + (size_t)row * 64 + j] = fminf(acc, 10.0f);
        __syncthreads();
    }
}

// ---------------- decoder loss ----------------
// one edge per 16 lanes; first NP*16 threads = pos, next NP*16 = neg.
__global__ __launch_bounds__(256) void k_loss(const int* __restrict__ pos,
                                              const int* __restrict__ neg,
                                              const float4* __restrict__ z4,
                                              float* __restrict__ accum) {
    int t = blockIdx.x * blockDim.x + threadIdx.x;
    int g = t >> 4, q = t & 15;
    bool isNeg = g >= NP;                  // block-uniform (NP*16 % 256 == 0)
    const int* idx = isNeg ? neg : pos;
    int e = isNeg ? g - NP : g;
    int a = idx[e], b = idx[NP + e];
    float4 va = z4[(size_t)a * 16 + q];
    float4 vb = z4[(size_t)b * 16 + q];
    float d = va.x * vb.x + va.y * vb.y + va.z * vb.z + va.w * vb.w;
    d += __shfl_xor(d, 1);
    d += __shfl_xor(d, 2);
    d += __shfl_xor(d, 4);
    d += __shfl_xor(d, 8);
    float term = 0.0f;
    if (q == 0) {
        float p = 1.0f / (1.0f + expf(-d));
        term = isNeg ? logf(1.0f - p + 1e-15f) : logf(p + 1e-15f);
    }
    __shared__ float bsum;
    if (threadIdx.x == 0) bsum = 0.0f;
    __syncthreads();
    if (q == 0) atomicAdd(&bsum, term);
    __syncthreads();
    if (threadIdx.x == 0) atomicAdd(&accum[isNeg ? 1 : 0], bsum);
}

__global__ void k_fin(const float* __restrict__ accum, float* __restrict__ out) {
    out[(size_t)NN * 128] = -(accum[0] + accum[1]) * (1.0f / (float)NP);
}

extern "C" void kernel_launch(void* const* d_in, const int* in_sizes, int n_in,
                              void* d_out, int out_size, void* d_ws, size_t ws_size,
                              hipStream_t stream) {
    const float* emb = (const float*)d_in[0];
    const int*   ei  = (const int*)d_in[1];
    const float* W1  = (const float*)d_in[2];
    const float* b1  = (const float*)d_in[3];
    const float* Wmu = (const float*)d_in[4];
    const float* bmu = (const float*)d_in[5];
    const float* Wls = (const float*)d_in[6];
    const float* bls = (const float*)d_in[7];
    const int*   pos = (const int*)d_in[8];
    const int*   neg = (const int*)d_in[9];
    float* out = (float*)d_out;

    char* ws = (char*)d_ws;
    float* dinv  = (float*)ws;                          // N floats
    int*   deg   = (int*)(ws + 512 * 1024);             // N ints
    float* accum = (float*)(ws + 1024 * 1024 - 256);    // 2 floats
    float* aggE  = (float*)(ws + 1024 * 1024);          // N*64 floats
    float* aggH  = (float*)(ws + 1024 * 1024);          // N*128 floats (reuses aggE region)
    float* h     = out;                                 // N*128 floats staged in d_out

    hipMemsetAsync(deg, 0, NN * sizeof(int), stream);
    hipMemsetAsync(accum, 0, 2 * sizeof(float), stream);

    k_deg <<<(NE + 255) / 256, 256, 0, stream>>>(ei, deg);
    k_dinv<<<(NN + 255) / 256, 256, 0, stream>>>(deg, dinv);

    k_selfE<<<(NN * 16 + 255) / 256, 256, 0, stream>>>((const float4*)emb, dinv, (float4*)aggE);
    k_edgeE<<<(NE * 16) / 256, 256, 0, stream>>>(ei, (const float4*)emb, dinv, aggE);

    k_h<<<NN / 16, 256, 0, stream>>>(aggE, W1, b1, h);

    k_selfH<<<(NN * 32 + 255) / 256, 256, 0, stream>>>((const float4*)h, dinv, (float4*)aggH);
    k_edgeH<<<(NE * 32) / 256, 256, 0, stream>>>(ei, (const float4*)h, dinv, aggH);

    k_out<<<NN / 16, 256, 0, stream>>>(aggH, Wmu, bmu, Wls, bls, out);

    k_loss<<<(2 * NP * 16) / 256, 256, 0, stream>>>(pos, neg, (const float4*)out, accum);
    k_fin<<<1, 1, 0, stream>>>(accum, out);
}

// Round 2
// 930.933 us; speedup vs baseline: 4.9075x; 4.9075x over previous
//
#include <hip/hip_runtime.h>
#include <hip/hip_bf16.h>

#define NN 100000      // nodes
#define NE 1600000     // edges
#define NP 100000      // pos/neg label edges
// EMB=64, HID=128, OUT=64

// ---------------- degree ----------------
__global__ void k_deg(const int* __restrict__ ei, int* __restrict__ deg) {
    int e = blockIdx.x * blockDim.x + threadIdx.x;
    if (e < NE) atomicAdd(&deg[ei[NE + e]], 1);
}

__global__ void k_dinv(const int* __restrict__ deg, float* __restrict__ dinv) {
    int i = blockIdx.x * blockDim.x + threadIdx.x;
    if (i < NN) dinv[i] = rsqrtf((float)deg[i] + 1.0f);
}

// ---------------- exclusive scan over deg -> rowptr (single workgroup) ----------------
__global__ __launch_bounds__(1024) void k_scan(const int* __restrict__ deg,
                                               int* __restrict__ rowptr) {
    __shared__ int part[1024];
    int t = threadIdx.x;
    const int CH = (NN + 1023) / 1024;   // 98
    int lo = t * CH, hi = min(lo + CH, NN);
    int s = 0;
    for (int i = lo; i < hi; ++i) s += deg[i];
    part[t] = s;
    __syncthreads();
    for (int off = 1; off < 1024; off <<= 1) {
        int add = (t >= off) ? part[t - off] : 0;
        __syncthreads();
        part[t] += add;
        __syncthreads();
    }
    int run = part[t] - s;               // exclusive prefix of this chunk
    for (int i = lo; i < hi; ++i) { rowptr[i] = run; run += deg[i]; }
    if (t == 1023) rowptr[NN] = run;
}

// ---------------- CSR scatter: edges grouped by dst ----------------
__global__ void k_scatter(const int* __restrict__ ei, const float* __restrict__ dinv,
                          const int* __restrict__ rowptr, int* __restrict__ cnt,
                          int2* __restrict__ edges) {
    int e = blockIdx.x * blockDim.x + threadIdx.x;
    if (e >= NE) return;
    int s = ei[e], d = ei[NE + e];
    int pos = rowptr[d] + atomicAdd(&cnt[d], 1);
    edges[pos] = make_int2(s, __float_as_int(dinv[s]));
}

// ---------------- gather-aggregate, 64 features: 16 lanes per dst row ----------------
// acc = x[r]*dinv[r]^2 + sum_j x[src_j]*dinv[src_j]*dinv[r]
__global__ __launch_bounds__(256) void k_aggE(const float4* __restrict__ x4,
                                              const float* __restrict__ dinv,
                                              const int* __restrict__ rowptr,
                                              const int2* __restrict__ edges,
                                              float4* __restrict__ agg4) {
    int t = blockIdx.x * blockDim.x + threadIdx.x;   // grid = NN*16 exactly
    int r = t >> 4, q = t & 15;
    float dr = dinv[r];
    float sc = dr * dr;
    float4 a = x4[(size_t)r * 16 + q];
    float4 acc = make_float4(a.x * sc, a.y * sc, a.z * sc, a.w * sc);
    int j = rowptr[r], j1 = rowptr[r + 1];
    if (j < j1) {
        int2 e = edges[j];
        while (j < j1) {
            int2 cur = e;
            ++j;
            if (j < j1) e = edges[j];            // prefetch next edge
            float w = __int_as_float(cur.y) * dr;
            float4 v = x4[(size_t)cur.x * 16 + q];
            acc.x = fmaf(v.x, w, acc.x); acc.y = fmaf(v.y, w, acc.y);
            acc.z = fmaf(v.z, w, acc.z); acc.w = fmaf(v.w, w, acc.w);
        }
    }
    agg4[t] = acc;
}

// ---------------- gather-aggregate, 128 features: 32 lanes per dst row ----------------
__global__ __launch_bounds__(256) void k_aggH(const float4* __restrict__ x4,
                                              const float* __restrict__ dinv,
                                              const int* __restrict__ rowptr,
                                              const int2* __restrict__ edges,
                                              float4* __restrict__ agg4) {
    int t = blockIdx.x * blockDim.x + threadIdx.x;   // grid = NN*32 exactly
    int r = t >> 5, q = t & 31;
    float dr = dinv[r];
    float sc = dr * dr;
    float4 a = x4[(size_t)r * 32 + q];
    float4 acc = make_float4(a.x * sc, a.y * sc, a.z * sc, a.w * sc);
    int j = rowptr[r], j1 = rowptr[r + 1];
    if (j < j1) {
        int2 e = edges[j];
        while (j < j1) {
            int2 cur = e;
            ++j;
            if (j < j1) e = edges[j];
            float w = __int_as_float(cur.y) * dr;
            float4 v = x4[(size_t)cur.x * 32 + q];
            acc.x = fmaf(v.x, w, acc.x); acc.y = fmaf(v.y, w, acc.y);
            acc.z = fmaf(v.z, w, acc.z); acc.w = fmaf(v.w, w, acc.w);
        }
    }
    agg4[t] = acc;
}

// ---------------- h = relu(aggE @ W1 + b1), [N,64]x[64,128] ----------------
__global__ __launch_bounds__(256) void k_h(const float* __restrict__ aggE,
                                           const float* __restrict__ W1,
                                           const float* __restrict__ b1,
                                           float* __restrict__ h) {
    __shared__ float w[64 * 128];
    __shared__ float rows[2][64];
    int t = threadIdx.x;
    for (int k = t; k < 64 * 128; k += 256) w[k] = W1[k];
    __syncthreads();
    int rsel = t >> 7, j = t & 127;
    float bias = b1[j];
    int base = blockIdx.x * 16;
    for (int r0 = 0; r0 < 16; r0 += 2) {
        if (t < 128) rows[t >> 6][t & 63] = aggE[(size_t)(base + r0 + (t >> 6)) * 64 + (t & 63)];
        __syncthreads();
        float acc = bias;
#pragma unroll
        for (int k = 0; k < 64; ++k) acc = fmaf(rows[rsel][k], w[k * 128 + j], acc);
        h[(size_t)(base + r0 + rsel) * 128 + j] = fmaxf(acc, 0.0f);
        __syncthreads();
    }
}

// ---------------- mu/logstd = aggH @ {W_mu,W_ls} + b, [N,128]x[128,64] ----------------
__global__ __launch_bounds__(256) void k_out(const float* __restrict__ aggH,
                                             const float* __restrict__ Wmu,
                                             const float* __restrict__ bmu,
                                             const float* __restrict__ Wls,
                                             const float* __restrict__ bls,
                                             float* __restrict__ out) {
    __shared__ float w[2][128 * 64];
    __shared__ float rows[2][128];
    int t = threadIdx.x;
    for (int k = t; k < 128 * 64; k += 256) { w[0][k] = Wmu[k]; w[1][k] = Wls[k]; }
    __syncthreads();
    int rsel = t >> 7;
    int u = t & 127;
    int which = u >> 6;         // 0 = mu, 1 = logstd (wave-uniform)
    int j = u & 63;
    float bias = which ? bls[j] : bmu[j];
    int base = blockIdx.x * 16;
    for (int r0 = 0; r0 < 16; r0 += 2) {
        rows[t >> 7][t & 127] = aggH[(size_t)(base + r0 + (t >> 7)) * 128 + (t & 127)];
        __syncthreads();
        int row = base + r0 + rsel;
        float acc = bias;
#pragma unroll
        for (int k = 0; k < 128; ++k) acc = fmaf(rows[rsel][k], w[which][k * 64 + j], acc);
        if (which == 0) out[(size_t)row * 64 + j] = acc;
        else            out[(size_t)NN * 64 + (size_t)row * 64 + j] = fminf(acc, 10.0f);
        __syncthreads();
    }
}

// ---------------- decoder loss ----------------
__global__ __launch_bounds__(256) void k_loss(const int* __restrict__ pos,
                                              const int* __restrict__ neg,
                                              const float4* __restrict__ z4,
                                              float* __restrict__ accum) {
    int t = blockIdx.x * blockDim.x + threadIdx.x;
    int g = t >> 4, q = t & 15;
    bool isNeg = g >= NP;                  // block-uniform (NP*16 % 256 == 0)
    const int* idx = isNeg ? neg : pos;
    int e = isNeg ? g - NP : g;
    int a = idx[e], b = idx[NP + e];
    float4 va = z4[(size_t)a * 16 + q];
    float4 vb = z4[(size_t)b * 16 + q];
    float d = va.x * vb.x + va.y * vb.y + va.z * vb.z + va.w * vb.w;
    d += __shfl_xor(d, 1);
    d += __shfl_xor(d, 2);
    d += __shfl_xor(d, 4);
    d += __shfl_xor(d, 8);
    float term = 0.0f;
    if (q == 0) {
        float p = 1.0f / (1.0f + expf(-d));
        term = isNeg ? logf(1.0f - p + 1e-15f) : logf(p + 1e-15f);
    }
    __shared__ float bsum;
    if (threadIdx.x == 0) bsum = 0.0f;
    __syncthreads();
    if (q == 0) atomicAdd(&bsum, term);
    __syncthreads();
    if (threadIdx.x == 0) atomicAdd(&accum[isNeg ? 1 : 0], bsum);
}

__global__ void k_fin(const float* __restrict__ accum, float* __restrict__ out) {
    out[(size_t)NN * 128] = -(accum[0] + accum[1]) * (1.0f / (float)NP);
}

extern "C" void kernel_launch(void* const* d_in, const int* in_sizes, int n_in,
                              void* d_out, int out_size, void* d_ws, size_t ws_size,
                              hipStream_t stream) {
    const float* emb = (const float*)d_in[0];
    const int*   ei  = (const int*)d_in[1];
    const float* W1  = (const float*)d_in[2];
    const float* b1  = (const float*)d_in[3];
    const float* Wmu = (const float*)d_in[4];
    const float* bmu = (const float*)d_in[5];
    const float* Wls = (const float*)d_in[6];
    const float* bls = (const float*)d_in[7];
    const int*   pos = (const int*)d_in[8];
    const int*   neg = (const int*)d_in[9];
    float* out = (float*)d_out;

    char* ws = (char*)d_ws;
    float* dinv   = (float*)(ws);                        // 400 KB
    int*   deg    = (int*)  (ws + (512 << 10));          // 400 KB
    int*   cnt    = (int*)  (ws + (1024 << 10));         // 400 KB
    int*   rowptr = (int*)  (ws + (1536 << 10));         // 400 KB + 4
    float* accum  = (float*)(ws + (2048 << 10));         // 8 B
    int2*  edges  = (int2*) (ws + (2048 << 10) + 256);   // 12.8 MB
    float* agg    = (float*)(ws + (16384 << 10));        // 51.2 MB (aggE then aggH)
    float* aggE   = agg;
    float* aggH   = agg;                                 // reuse after aggE dead
    float* h      = out;                                 // N*128 floats staged in d_out

    hipMemsetAsync(deg, 0, NN * sizeof(int), stream);
    hipMemsetAsync(cnt, 0, NN * sizeof(int), stream);
    hipMemsetAsync(accum, 0, 2 * sizeof(float), stream);

    k_deg    <<<(NE + 255) / 256, 256, 0, stream>>>(ei, deg);
    k_dinv   <<<(NN + 255) / 256, 256, 0, stream>>>(deg, dinv);
    k_scan   <<<1, 1024, 0, stream>>>(deg, rowptr);
    k_scatter<<<(NE + 255) / 256, 256, 0, stream>>>(ei, dinv, rowptr, cnt, edges);

    k_aggE<<<(NN * 16) / 256, 256, 0, stream>>>((const float4*)emb, dinv, rowptr, edges,
                                                (float4*)aggE);
    k_h<<<NN / 16, 256, 0, stream>>>(aggE, W1, b1, h);

    k_aggH<<<(NN * 32) / 256, 256, 0, stream>>>((const float4*)h, dinv, rowptr, edges,
                                                (float4*)aggH);
    k_out<<<NN / 16, 256, 0, stream>>>(aggH, Wmu, bmu, Wls, bls, out);

    k_loss<<<(2 * NP * 16) / 256, 256, 0, stream>>>(pos, neg, (const float4*)out, accum);
    k_fin<<<1, 1, 0, stream>>>(accum, out);
}

// Round 3
// 615.356 us; speedup vs baseline: 7.4242x; 1.5128x over previous
//
#include <hip/hip_runtime.h>
#include <hip/hip_bf16.h>

#define NN 100000      // nodes
#define NE 1600000     // edges
#define NP 100000      // pos/neg label edges
// EMB=64, HID=128, OUT=64

// ---------------- degree ----------------
__global__ void k_deg(const int* __restrict__ ei, int* __restrict__ deg) {
    int e = blockIdx.x * blockDim.x + threadIdx.x;
    if (e < NE) atomicAdd(&deg[ei[NE + e]], 1);
}

__global__ void k_dinv(const int* __restrict__ deg, float* __restrict__ dinv) {
    int i = blockIdx.x * blockDim.x + threadIdx.x;
    if (i < NN) dinv[i] = rsqrtf((float)deg[i] + 1.0f);
}

// ---------------- exclusive scan over deg -> rowptr (single workgroup, int4) ----------------
__global__ __launch_bounds__(1024) void k_scan(const int* __restrict__ deg,
                                               int* __restrict__ rowptr) {
    __shared__ int part[1024];
    int t = threadIdx.x;
    int lo = t * 100;                       // 1000 active threads, 100 each
    int s = 0;
    if (lo < NN) {
        const int4* d4 = (const int4*)(deg + lo);
#pragma unroll
        for (int i = 0; i < 25; ++i) { int4 d = d4[i]; s += d.x + d.y + d.z + d.w; }
    }
    part[t] = s;
    __syncthreads();
    for (int off = 1; off < 1024; off <<= 1) {
        int add = (t >= off) ? part[t - off] : 0;
        __syncthreads();
        part[t] += add;
        __syncthreads();
    }
    int run = part[t] - s;                  // exclusive prefix
    if (lo < NN) {
        const int4* d4 = (const int4*)(deg + lo);
        int4* r4 = (int4*)(rowptr + lo);
#pragma unroll
        for (int i = 0; i < 25; ++i) {
            int4 d = d4[i];
            r4[i] = make_int4(run, run + d.x, run + d.x + d.y, run + d.x + d.y + d.z);
            run += d.x + d.y + d.z + d.w;
        }
        if (t == 999) rowptr[NN] = run;
    }
}

// ---------------- CSR scatter: edges grouped by dst ----------------
__global__ void k_scatter(const int* __restrict__ ei, const float* __restrict__ dinv,
                          const int* __restrict__ rowptr, int* __restrict__ cnt,
                          int2* __restrict__ edges) {
    int e = blockIdx.x * blockDim.x + threadIdx.x;
    if (e >= NE) return;
    int s = ei[e], d = ei[NE + e];
    int pos = rowptr[d] + atomicAdd(&cnt[d], 1);
    edges[pos] = make_int2(s, __float_as_int(dinv[s]));
}

// ---------------- gather-aggregate, 64 features: 16 lanes per dst row ----------------
__global__ __launch_bounds__(256) void k_aggE(const float4* __restrict__ x4,
                                              const float* __restrict__ dinv,
                                              const int* __restrict__ rowptr,
                                              const int2* __restrict__ edges,
                                              float4* __restrict__ agg4) {
    int t = blockIdx.x * blockDim.x + threadIdx.x;   // grid = NN*16 exactly
    int r = t >> 4, q = t & 15;
    float dr = dinv[r];
    float sc = dr * dr;
    float4 a = x4[(size_t)r * 16 + q];
    float4 acc = make_float4(a.x * sc, a.y * sc, a.z * sc, a.w * sc);
    int j = rowptr[r], j1 = rowptr[r + 1];
    for (; j + 4 <= j1; j += 4) {
        int2 e0 = edges[j], e1 = edges[j + 1], e2 = edges[j + 2], e3 = edges[j + 3];
        float4 v0 = x4[(size_t)e0.x * 16 + q];
        float4 v1 = x4[(size_t)e1.x * 16 + q];
        float4 v2 = x4[(size_t)e2.x * 16 + q];
        float4 v3 = x4[(size_t)e3.x * 16 + q];
        float w0 = __int_as_float(e0.y) * dr, w1 = __int_as_float(e1.y) * dr;
        float w2 = __int_as_float(e2.y) * dr, w3 = __int_as_float(e3.y) * dr;
        acc.x = fmaf(v0.x, w0, acc.x); acc.y = fmaf(v0.y, w0, acc.y);
        acc.z = fmaf(v0.z, w0, acc.z); acc.w = fmaf(v0.w, w0, acc.w);
        acc.x = fmaf(v1.x, w1, acc.x); acc.y = fmaf(v1.y, w1, acc.y);
        acc.z = fmaf(v1.z, w1, acc.z); acc.w = fmaf(v1.w, w1, acc.w);
        acc.x = fmaf(v2.x, w2, acc.x); acc.y = fmaf(v2.y, w2, acc.y);
        acc.z = fmaf(v2.z, w2, acc.z); acc.w = fmaf(v2.w, w2, acc.w);
        acc.x = fmaf(v3.x, w3, acc.x); acc.y = fmaf(v3.y, w3, acc.y);
        acc.z = fmaf(v3.z, w3, acc.z); acc.w = fmaf(v3.w, w3, acc.w);
    }
    for (; j < j1; ++j) {
        int2 e = edges[j];
        float w = __int_as_float(e.y) * dr;
        float4 v = x4[(size_t)e.x * 16 + q];
        acc.x = fmaf(v.x, w, acc.x); acc.y = fmaf(v.y, w, acc.y);
        acc.z = fmaf(v.z, w, acc.z); acc.w = fmaf(v.w, w, acc.w);
    }
    agg4[t] = acc;
}

// ---------------- gather-aggregate, 128 features: 32 lanes per dst row ----------------
__global__ __launch_bounds__(256) void k_aggH(const float4* __restrict__ x4,
                                              const float* __restrict__ dinv,
                                              const int* __restrict__ rowptr,
                                              const int2* __restrict__ edges,
                                              float4* __restrict__ agg4) {
    int t = blockIdx.x * blockDim.x + threadIdx.x;   // grid = NN*32 exactly
    int r = t >> 5, q = t & 31;
    float dr = dinv[r];
    float sc = dr * dr;
    float4 a = x4[(size_t)r * 32 + q];
    float4 acc = make_float4(a.x * sc, a.y * sc, a.z * sc, a.w * sc);
    int j = rowptr[r], j1 = rowptr[r + 1];
    for (; j + 4 <= j1; j += 4) {
        int2 e0 = edges[j], e1 = edges[j + 1], e2 = edges[j + 2], e3 = edges[j + 3];
        float4 v0 = x4[(size_t)e0.x * 32 + q];
        float4 v1 = x4[(size_t)e1.x * 32 + q];
        float4 v2 = x4[(size_t)e2.x * 32 + q];
        float4 v3 = x4[(size_t)e3.x * 32 + q];
        float w0 = __int_as_float(e0.y) * dr, w1 = __int_as_float(e1.y) * dr;
        float w2 = __int_as_float(e2.y) * dr, w3 = __int_as_float(e3.y) * dr;
        acc.x = fmaf(v0.x, w0, acc.x); acc.y = fmaf(v0.y, w0, acc.y);
        acc.z = fmaf(v0.z, w0, acc.z); acc.w = fmaf(v0.w, w0, acc.w);
        acc.x = fmaf(v1.x, w1, acc.x); acc.y = fmaf(v1.y, w1, acc.y);
        acc.z = fmaf(v1.z, w1, acc.z); acc.w = fmaf(v1.w, w1, acc.w);
        acc.x = fmaf(v2.x, w2, acc.x); acc.y = fmaf(v2.y, w2, acc.y);
        acc.z = fmaf(v2.z, w2, acc.z); acc.w = fmaf(v2.w, w2, acc.w);
        acc.x = fmaf(v3.x, w3, acc.x); acc.y = fmaf(v3.y, w3, acc.y);
        acc.z = fmaf(v3.z, w3, acc.z); acc.w = fmaf(v3.w, w3, acc.w);
    }
    for (; j < j1; ++j) {
        int2 e = edges[j];
        float w = __int_as_float(e.y) * dr;
        float4 v = x4[(size_t)e.x * 32 + q];
        acc.x = fmaf(v.x, w, acc.x); acc.y = fmaf(v.y, w, acc.y);
        acc.z = fmaf(v.z, w, acc.z); acc.w = fmaf(v.w, w, acc.w);
    }
    agg4[t] = acc;
}

// ---------------- h = relu(aggE @ W1 + b1), [N,64]x[64,128], 4x4 register tile ----------------
// 256 threads, 32 rows/block. LDS: W1 (32KB) + rows (8.3KB).
__global__ __launch_bounds__(256) void k_h(const float* __restrict__ aggE,
                                           const float4* __restrict__ W1_4,  // [64][32] f4
                                           const float* __restrict__ b1,
                                           float4* __restrict__ h4) {
    __shared__ float4 w4[64 * 32];     // w4[k*32+jg] = W1[k][4jg..4jg+3]
    __shared__ float rows[32 * 65];    // padded
    int t = threadIdx.x;
    int base = blockIdx.x * 32;
#pragma unroll
    for (int i = 0; i < 8; ++i) w4[t + i * 256] = W1_4[t + i * 256];
#pragma unroll
    for (int i = 0; i < 8; ++i) {
        int idx = t + i * 256;
        int r = idx >> 6, kk = idx & 63;
        rows[r * 65 + kk] = aggE[(size_t)(base + r) * 64 + kk];
    }
    __syncthreads();
    int rg = t >> 5, jg = t & 31;
    int r0 = rg * 4;
    float4 bias = ((const float4*)b1)[jg];
    float acc[4][4];
#pragma unroll
    for (int r = 0; r < 4; ++r) {
        acc[r][0] = bias.x; acc[r][1] = bias.y; acc[r][2] = bias.z; acc[r][3] = bias.w;
    }
#pragma unroll 8
    for (int k = 0; k < 64; ++k) {
        float4 w = w4[k * 32 + jg];
        float rv0 = rows[(r0 + 0) * 65 + k];
        float rv1 = rows[(r0 + 1) * 65 + k];
        float rv2 = rows[(r0 + 2) * 65 + k];
        float rv3 = rows[(r0 + 3) * 65 + k];
        acc[0][0] = fmaf(rv0, w.x, acc[0][0]); acc[0][1] = fmaf(rv0, w.y, acc[0][1]);
        acc[0][2] = fmaf(rv0, w.z, acc[0][2]); acc[0][3] = fmaf(rv0, w.w, acc[0][3]);
        acc[1][0] = fmaf(rv1, w.x, acc[1][0]); acc[1][1] = fmaf(rv1, w.y, acc[1][1]);
        acc[1][2] = fmaf(rv1, w.z, acc[1][2]); acc[1][3] = fmaf(rv1, w.w, acc[1][3]);
        acc[2][0] = fmaf(rv2, w.x, acc[2][0]); acc[2][1] = fmaf(rv2, w.y, acc[2][1]);
        acc[2][2] = fmaf(rv2, w.z, acc[2][2]); acc[2][3] = fmaf(rv2, w.w, acc[2][3]);
        acc[3][0] = fmaf(rv3, w.x, acc[3][0]); acc[3][1] = fmaf(rv3, w.y, acc[3][1]);
        acc[3][2] = fmaf(rv3, w.z, acc[3][2]); acc[3][3] = fmaf(rv3, w.w, acc[3][3]);
    }
#pragma unroll
    for (int r = 0; r < 4; ++r) {
        float4 o = make_float4(fmaxf(acc[r][0], 0.0f), fmaxf(acc[r][1], 0.0f),
                               fmaxf(acc[r][2], 0.0f), fmaxf(acc[r][3], 0.0f));
        h4[(size_t)(base + r0 + r) * 32 + jg] = o;
    }
}

// ---------------- mu/logstd = aggH @ [Wmu|Wls] + b, [N,128]x[128,128], 4x4 tile ----------------
// 256 threads, 32 rows/block. LDS: W half (32KB, restaged per k-half) + rows (16.5KB).
__global__ __launch_bounds__(256) void k_out(const float* __restrict__ aggH,
                                             const float4* __restrict__ Wmu4, // [128][16] f4
                                             const float* __restrict__ bmu,
                                             const float4* __restrict__ Wls4, // [128][16] f4
                                             const float* __restrict__ bls,
                                             float* __restrict__ out) {
    __shared__ float4 w4[64 * 32];     // w4[kk*32+jj] = W[kh*64+kk][4jj..4jj+3] combined
    __shared__ float rows[32 * 129];   // padded, full 128 feats
    int t = threadIdx.x;
    int base = blockIdx.x * 32;
#pragma unroll
    for (int i = 0; i < 16; ++i) {
        int idx = t + i * 256;
        int r = idx >> 7, kk = idx & 127;
        rows[r * 129 + kk] = aggH[(size_t)(base + r) * 128 + kk];
    }
    int rg = t >> 5, jg = t & 31;
    int r0 = rg * 4;
    float4 bias = (jg < 16) ? ((const float4*)bmu)[jg] : ((const float4*)bls)[jg - 16];
    float acc[4][4];
#pragma unroll
    for (int r = 0; r < 4; ++r) {
        acc[r][0] = bias.x; acc[r][1] = bias.y; acc[r][2] = bias.z; acc[r][3] = bias.w;
    }
    for (int kh = 0; kh < 2; ++kh) {
        if (kh) __syncthreads();      // all waves done reading previous w4
#pragma unroll
        for (int i = 0; i < 8; ++i) {
            int idx = t + i * 256;
            int jj = idx & 31, kk = idx >> 5;
            int k = kh * 64 + kk;
            w4[idx] = (jj < 16) ? Wmu4[k * 16 + jj] : Wls4[k * 16 + (jj - 16)];
        }
        __syncthreads();
#pragma unroll 8
        for (int kk = 0; kk < 64; ++kk) {
            int k = kh * 64 + kk;
            float4 w = w4[kk * 32 + jg];
            float rv0 = rows[(r0 + 0) * 129 + k];
            float rv1 = rows[(r0 + 1) * 129 + k];
            float rv2 = rows[(r0 + 2) * 129 + k];
            float rv3 = rows[(r0 + 3) * 129 + k];
            acc[0][0] = fmaf(rv0, w.x, acc[0][0]); acc[0][1] = fmaf(rv0, w.y, acc[0][1]);
            acc[0][2] = fmaf(rv0, w.z, acc[0][2]); acc[0][3] = fmaf(rv0, w.w, acc[0][3]);
            acc[1][0] = fmaf(rv1, w.x, acc[1][0]); acc[1][1] = fmaf(rv1, w.y, acc[1][1]);
            acc[1][2] = fmaf(rv1, w.z, acc[1][2]); acc[1][3] = fmaf(rv1, w.w, acc[1][3]);
            acc[2][0] = fmaf(rv2, w.x, acc[2][0]); acc[2][1] = fmaf(rv2, w.y, acc[2][1]);
            acc[2][2] = fmaf(rv2, w.z, acc[2][2]); acc[2][3] = fmaf(rv2, w.w, acc[2][3]);
            acc[3][0] = fmaf(rv3, w.x, acc[3][0]); acc[3][1] = fmaf(rv3, w.y, acc[3][1]);
            acc[3][2] = fmaf(rv3, w.z, acc[3][2]); acc[3][3] = fmaf(rv3, w.w, acc[3][3]);
        }
    }
    float4* out4 = (float4*)out;
    if (jg < 16) {
#pragma unroll
        for (int r = 0; r < 4; ++r) {
            out4[(size_t)(base + r0 + r) * 16 + jg] =
                make_float4(acc[r][0], acc[r][1], acc[r][2], acc[r][3]);
        }
    } else {
#pragma unroll
        for (int r = 0; r < 4; ++r) {
            float4 o = make_float4(fminf(acc[r][0], 10.0f), fminf(acc[r][1], 10.0f),
                                   fminf(acc[r][2], 10.0f), fminf(acc[r][3], 10.0f));
            out4[(size_t)NN * 16 + (size_t)(base + r0 + r) * 16 + (jg - 16)] = o;
        }
    }
}

// ---------------- decoder loss ----------------
__global__ __launch_bounds__(256) void k_loss(const int* __restrict__ pos,
                                              const int* __restrict__ neg,
                                              const float4* __restrict__ z4,
                                              float* __restrict__ accum) {
    int t = blockIdx.x * blockDim.x + threadIdx.x;
    int g = t >> 4, q = t & 15;
    bool isNeg = g >= NP;                  // block-uniform (NP*16 % 256 == 0)
    const int* idx = isNeg ? neg : pos;
    int e = isNeg ? g - NP : g;
    int a = idx[e], b = idx[NP + e];
    float4 va = z4[(size_t)a * 16 + q];
    float4 vb = z4[(size_t)b * 16 + q];
    float d = va.x * vb.x + va.y * vb.y + va.z * vb.z + va.w * vb.w;
    d += __shfl_xor(d, 1);
    d += __shfl_xor(d, 2);
    d += __shfl_xor(d, 4);
    d += __shfl_xor(d, 8);
    float term = 0.0f;
    if (q == 0) {
        float p = 1.0f / (1.0f + expf(-d));
        term = isNeg ? logf(1.0f - p + 1e-15f) : logf(p + 1e-15f);
    }
    __shared__ float bsum;
    if (threadIdx.x == 0) bsum = 0.0f;
    __syncthreads();
    if (q == 0) atomicAdd(&bsum, term);
    __syncthreads();
    if (threadIdx.x == 0) atomicAdd(&accum[isNeg ? 1 : 0], bsum);
}

__global__ void k_fin(const float* __restrict__ accum, float* __restrict__ out) {
    out[(size_t)NN * 128] = -(accum[0] + accum[1]) * (1.0f / (float)NP);
}

extern "C" void kernel_launch(void* const* d_in, const int* in_sizes, int n_in,
                              void* d_out, int out_size, void* d_ws, size_t ws_size,
                              hipStream_t stream) {
    const float* emb = (const float*)d_in[0];
    const int*   ei  = (const int*)d_in[1];
    const float* W1  = (const float*)d_in[2];
    const float* b1  = (const float*)d_in[3];
    const float* Wmu = (const float*)d_in[4];
    const float* bmu = (const float*)d_in[5];
    const float* Wls = (const float*)d_in[6];
    const float* bls = (const float*)d_in[7];
    const int*   pos = (const int*)d_in[8];
    const int*   neg = (const int*)d_in[9];
    float* out = (float*)d_out;

    char* ws = (char*)d_ws;
    float* dinv   = (float*)(ws);                        // 400 KB
    int*   deg    = (int*)  (ws + (512 << 10));          // 400 KB
    int*   cnt    = (int*)  (ws + (1024 << 10));         // 400 KB
    int*   rowptr = (int*)  (ws + (1536 << 10));         // 400 KB + 4
    float* accum  = (float*)(ws + (2048 << 10));         // 8 B
    int2*  edges  = (int2*) (ws + (2048 << 10) + 256);   // 12.8 MB
    float* agg    = (float*)(ws + (16384 << 10));        // 51.2 MB (aggE then aggH)
    float* aggE   = agg;
    float* aggH   = agg;                                 // reuse after aggE dead
    float* h      = out;                                 // N*128 floats staged in d_out

    hipMemsetAsync(deg, 0, NN * sizeof(int), stream);
    hipMemsetAsync(cnt, 0, NN * sizeof(int), stream);
    hipMemsetAsync(accum, 0, 2 * sizeof(float), stream);

    k_deg    <<<(NE + 255) / 256, 256, 0, stream>>>(ei, deg);
    k_dinv   <<<(NN + 255) / 256, 256, 0, stream>>>(deg, dinv);
    k_scan   <<<1, 1024, 0, stream>>>(deg, rowptr);
    k_scatter<<<(NE + 255) / 256, 256, 0, stream>>>(ei, dinv, rowptr, cnt, edges);

    k_aggE<<<(NN * 16) / 256, 256, 0, stream>>>((const float4*)emb, dinv, rowptr, edges,
                                                (float4*)aggE);
    k_h<<<NN / 32, 256, 0, stream>>>(aggE, (const float4*)W1, b1, (float4*)h);

    k_aggH<<<(NN * 32) / 256, 256, 0, stream>>>((const float4*)h, dinv, rowptr, edges,
                                                (float4*)aggH);
    k_out<<<NN / 32, 256, 0, stream>>>(aggH, (const float4*)Wmu, bmu,
                                       (const float4*)Wls, bls, out);

    k_loss<<<(2 * NP * 16) / 256, 256, 0, stream>>>(pos, neg, (const float4*)out, accum);
    k_fin<<<1, 1, 0, stream>>>(accum, out);
}

// Round 4
// 509.002 us; speedup vs baseline: 8.9755x; 1.2089x over previous
//
#include <hip/hip_runtime.h>
#include <hip/hip_bf16.h>

#define NN 100000      // nodes
#define NE 1600000     // edges
#define NP 100000      // pos/neg label edges
// EMB=64, HID=128, OUT=64

// ---------------- degree ----------------
__global__ void k_deg(const int* __restrict__ ei, int* __restrict__ deg) {
    int e = blockIdx.x * blockDim.x + threadIdx.x;
    if (e < NE) atomicAdd(&deg[ei[NE + e]], 1);
}

__global__ void k_dinv(const int* __restrict__ deg, float* __restrict__ dinv) {
    int i = blockIdx.x * blockDim.x + threadIdx.x;
    if (i < NN) dinv[i] = rsqrtf((float)deg[i] + 1.0f);
}

// ---------------- exclusive scan over deg -> rowptr (single workgroup, int4) ----------------
__global__ __launch_bounds__(1024) void k_scan(const int* __restrict__ deg,
                                               int* __restrict__ rowptr) {
    __shared__ int part[1024];
    int t = threadIdx.x;
    int lo = t * 100;                       // 1000 active threads, 100 each
    int s = 0;
    if (lo < NN) {
        const int4* d4 = (const int4*)(deg + lo);
#pragma unroll
        for (int i = 0; i < 25; ++i) { int4 d = d4[i]; s += d.x + d.y + d.z + d.w; }
    }
    part[t] = s;
    __syncthreads();
    for (int off = 1; off < 1024; off <<= 1) {
        int add = (t >= off) ? part[t - off] : 0;
        __syncthreads();
        part[t] += add;
        __syncthreads();
    }
    int run = part[t] - s;                  // exclusive prefix
    if (lo < NN) {
        const int4* d4 = (const int4*)(deg + lo);
        int4* r4 = (int4*)(rowptr + lo);
#pragma unroll
        for (int i = 0; i < 25; ++i) {
            int4 d = d4[i];
            r4[i] = make_int4(run, run + d.x, run + d.x + d.y, run + d.x + d.y + d.z);
            run += d.x + d.y + d.z + d.w;
        }
        if (t == 999) rowptr[NN] = run;
    }
}

// ---------------- CSR scatter: edges grouped by dst ----------------
__global__ void k_scatter(const int* __restrict__ ei, const float* __restrict__ dinv,
                          const int* __restrict__ rowptr, int* __restrict__ cnt,
                          int2* __restrict__ edges) {
    int e = blockIdx.x * blockDim.x + threadIdx.x;
    if (e >= NE) return;
    int s = ei[e], d = ei[NE + e];
    int pos = rowptr[d] + atomicAdd(&cnt[d], 1);
    edges[pos] = make_int2(s, __float_as_int(dinv[s]));
}

// ---------------- gather-aggregate, 64 features: 16 lanes per dst row ----------------
__global__ __launch_bounds__(256) void k_aggE(const float4* __restrict__ x4,
                                              const float* __restrict__ dinv,
                                              const int* __restrict__ rowptr,
                                              const int2* __restrict__ edges,
                                              float4* __restrict__ agg4) {
    int t = blockIdx.x * blockDim.x + threadIdx.x;   // grid = NN*16 exactly
    int r = t >> 4, q = t & 15;
    float dr = dinv[r];
    float sc = dr * dr;
    float4 a = x4[(size_t)r * 16 + q];
    float4 acc = make_float4(a.x * sc, a.y * sc, a.z * sc, a.w * sc);
    int j = rowptr[r], j1 = rowptr[r + 1];
    for (; j + 4 <= j1; j += 4) {
        int2 e0 = edges[j], e1 = edges[j + 1], e2 = edges[j + 2], e3 = edges[j + 3];
        float4 v0 = x4[(size_t)e0.x * 16 + q];
        float4 v1 = x4[(size_t)e1.x * 16 + q];
        float4 v2 = x4[(size_t)e2.x * 16 + q];
        float4 v3 = x4[(size_t)e3.x * 16 + q];
        float w0 = __int_as_float(e0.y) * dr, w1 = __int_as_float(e1.y) * dr;
        float w2 = __int_as_float(e2.y) * dr, w3 = __int_as_float(e3.y) * dr;
        acc.x = fmaf(v0.x, w0, acc.x); acc.y = fmaf(v0.y, w0, acc.y);
        acc.z = fmaf(v0.z, w0, acc.z); acc.w = fmaf(v0.w, w0, acc.w);
        acc.x = fmaf(v1.x, w1, acc.x); acc.y = fmaf(v1.y, w1, acc.y);
        acc.z = fmaf(v1.z, w1, acc.z); acc.w = fmaf(v1.w, w1, acc.w);
        acc.x = fmaf(v2.x, w2, acc.x); acc.y = fmaf(v2.y, w2, acc.y);
        acc.z = fmaf(v2.z, w2, acc.z); acc.w = fmaf(v2.w, w2, acc.w);
        acc.x = fmaf(v3.x, w3, acc.x); acc.y = fmaf(v3.y, w3, acc.y);
        acc.z = fmaf(v3.z, w3, acc.z); acc.w = fmaf(v3.w, w3, acc.w);
    }
    for (; j < j1; ++j) {
        int2 e = edges[j];
        float w = __int_as_float(e.y) * dr;
        float4 v = x4[(size_t)e.x * 16 + q];
        acc.x = fmaf(v.x, w, acc.x); acc.y = fmaf(v.y, w, acc.y);
        acc.z = fmaf(v.z, w, acc.z); acc.w = fmaf(v.w, w, acc.w);
    }
    agg4[t] = acc;
}

// ---------------- gather-aggregate, 128 features: 32 lanes per dst row ----------------
__global__ __launch_bounds__(256) void k_aggH(const float4* __restrict__ x4,
                                              const float* __restrict__ dinv,
                                              const int* __restrict__ rowptr,
                                              const int2* __restrict__ edges,
                                              float4* __restrict__ agg4) {
    int t = blockIdx.x * blockDim.x + threadIdx.x;   // grid = NN*32 exactly
    int r = t >> 5, q = t & 31;
    float dr = dinv[r];
    float sc = dr * dr;
    float4 a = x4[(size_t)r * 32 + q];
    float4 acc = make_float4(a.x * sc, a.y * sc, a.z * sc, a.w * sc);
    int j = rowptr[r], j1 = rowptr[r + 1];
    for (; j + 4 <= j1; j += 4) {
        int2 e0 = edges[j], e1 = edges[j + 1], e2 = edges[j + 2], e3 = edges[j + 3];
        float4 v0 = x4[(size_t)e0.x * 32 + q];
        float4 v1 = x4[(size_t)e1.x * 32 + q];
        float4 v2 = x4[(size_t)e2.x * 32 + q];
        float4 v3 = x4[(size_t)e3.x * 32 + q];
        float w0 = __int_as_float(e0.y) * dr, w1 = __int_as_float(e1.y) * dr;
        float w2 = __int_as_float(e2.y) * dr, w3 = __int_as_float(e3.y) * dr;
        acc.x = fmaf(v0.x, w0, acc.x); acc.y = fmaf(v0.y, w0, acc.y);
        acc.z = fmaf(v0.z, w0, acc.z); acc.w = fmaf(v0.w, w0, acc.w);
        acc.x = fmaf(v1.x, w1, acc.x); acc.y = fmaf(v1.y, w1, acc.y);
        acc.z = fmaf(v1.z, w1, acc.z); acc.w = fmaf(v1.w, w1, acc.w);
        acc.x = fmaf(v2.x, w2, acc.x); acc.y = fmaf(v2.y, w2, acc.y);
        acc.z = fmaf(v2.z, w2, acc.z); acc.w = fmaf(v2.w, w2, acc.w);
        acc.x = fmaf(v3.x, w3, acc.x); acc.y = fmaf(v3.y, w3, acc.y);
        acc.z = fmaf(v3.z, w3, acc.z); acc.w = fmaf(v3.w, w3, acc.w);
    }
    for (; j < j1; ++j) {
        int2 e = edges[j];
        float w = __int_as_float(e.y) * dr;
        float4 v = x4[(size_t)e.x * 32 + q];
        acc.x = fmaf(v.x, w, acc.x); acc.y = fmaf(v.y, w, acc.y);
        acc.z = fmaf(v.z, w, acc.z); acc.w = fmaf(v.w, w, acc.w);
    }
    agg4[t] = acc;
}

// ---------------- h = relu(aggE @ W1 + b1), [N,64]x[64,128], 4x4 register tile ----------------
__global__ __launch_bounds__(256) void k_h(const float* __restrict__ aggE,
                                           const float4* __restrict__ W1_4,  // [64][32] f4
                                           const float* __restrict__ b1,
                                           float4* __restrict__ h4) {
    __shared__ float4 w4[64 * 32];     // w4[k*32+jg] = W1[k][4jg..4jg+3]
    __shared__ float rows[32 * 65];    // padded
    int t = threadIdx.x;
    int base = blockIdx.x * 32;
#pragma unroll
    for (int i = 0; i < 8; ++i) w4[t + i * 256] = W1_4[t + i * 256];
#pragma unroll
    for (int i = 0; i < 8; ++i) {
        int idx = t + i * 256;
        int r = idx >> 6, kk = idx & 63;
        rows[r * 65 + kk] = aggE[(size_t)(base + r) * 64 + kk];
    }
    __syncthreads();
    int rg = t >> 5, jg = t & 31;
    int r0 = rg * 4;
    float4 bias = ((const float4*)b1)[jg];
    float acc[4][4];
#pragma unroll
    for (int r = 0; r < 4; ++r) {
        acc[r][0] = bias.x; acc[r][1] = bias.y; acc[r][2] = bias.z; acc[r][3] = bias.w;
    }
#pragma unroll 8
    for (int k = 0; k < 64; ++k) {
        float4 w = w4[k * 32 + jg];
        float rv0 = rows[(r0 + 0) * 65 + k];
        float rv1 = rows[(r0 + 1) * 65 + k];
        float rv2 = rows[(r0 + 2) * 65 + k];
        float rv3 = rows[(r0 + 3) * 65 + k];
        acc[0][0] = fmaf(rv0, w.x, acc[0][0]); acc[0][1] = fmaf(rv0, w.y, acc[0][1]);
        acc[0][2] = fmaf(rv0, w.z, acc[0][2]); acc[0][3] = fmaf(rv0, w.w, acc[0][3]);
        acc[1][0] = fmaf(rv1, w.x, acc[1][0]); acc[1][1] = fmaf(rv1, w.y, acc[1][1]);
        acc[1][2] = fmaf(rv1, w.z, acc[1][2]); acc[1][3] = fmaf(rv1, w.w, acc[1][3]);
        acc[2][0] = fmaf(rv2, w.x, acc[2][0]); acc[2][1] = fmaf(rv2, w.y, acc[2][1]);
        acc[2][2] = fmaf(rv2, w.z, acc[2][2]); acc[2][3] = fmaf(rv2, w.w, acc[2][3]);
        acc[3][0] = fmaf(rv3, w.x, acc[3][0]); acc[3][1] = fmaf(rv3, w.y, acc[3][1]);
        acc[3][2] = fmaf(rv3, w.z, acc[3][2]); acc[3][3] = fmaf(rv3, w.w, acc[3][3]);
    }
#pragma unroll
    for (int r = 0; r < 4; ++r) {
        float4 o = make_float4(fmaxf(acc[r][0], 0.0f), fmaxf(acc[r][1], 0.0f),
                               fmaxf(acc[r][2], 0.0f), fmaxf(acc[r][3], 0.0f));
        h4[(size_t)(base + r0 + r) * 32 + jg] = o;
    }
}

// ---------------- mu/logstd = aggH @ [Wmu|Wls] + b, [N,128]x[128,128], 4x4 tile ----------------
__global__ __launch_bounds__(256) void k_out(const float* __restrict__ aggH,
                                             const float4* __restrict__ Wmu4, // [128][16] f4
                                             const float* __restrict__ bmu,
                                             const float4* __restrict__ Wls4, // [128][16] f4
                                             const float* __restrict__ bls,
                                             float* __restrict__ out) {
    __shared__ float4 w4[64 * 32];     // w4[kk*32+jj] = W[kh*64+kk][4jj..4jj+3] combined
    __shared__ float rows[32 * 129];   // padded, full 128 feats
    int t = threadIdx.x;
    int base = blockIdx.x * 32;
#pragma unroll
    for (int i = 0; i < 16; ++i) {
        int idx = t + i * 256;
        int r = idx >> 7, kk = idx & 127;
        rows[r * 129 + kk] = aggH[(size_t)(base + r) * 128 + kk];
    }
    int rg = t >> 5, jg = t & 31;
    int r0 = rg * 4;
    float4 bias = (jg < 16) ? ((const float4*)bmu)[jg] : ((const float4*)bls)[jg - 16];
    float acc[4][4];
#pragma unroll
    for (int r = 0; r < 4; ++r) {
        acc[r][0] = bias.x; acc[r][1] = bias.y; acc[r][2] = bias.z; acc[r][3] = bias.w;
    }
    for (int kh = 0; kh < 2; ++kh) {
        if (kh) __syncthreads();      // all waves done reading previous w4
#pragma unroll
        for (int i = 0; i < 8; ++i) {
            int idx = t + i * 256;
            int jj = idx & 31, kk = idx >> 5;
            int k = kh * 64 + kk;
            w4[idx] = (jj < 16) ? Wmu4[k * 16 + jj] : Wls4[k * 16 + (jj - 16)];
        }
        __syncthreads();
#pragma unroll 8
        for (int kk = 0; kk < 64; ++kk) {
            int k = kh * 64 + kk;
            float4 w = w4[kk * 32 + jg];
            float rv0 = rows[(r0 + 0) * 129 + k];
            float rv1 = rows[(r0 + 1) * 129 + k];
            float rv2 = rows[(r0 + 2) * 129 + k];
            float rv3 = rows[(r0 + 3) * 129 + k];
            acc[0][0] = fmaf(rv0, w.x, acc[0][0]); acc[0][1] = fmaf(rv0, w.y, acc[0][1]);
            acc[0][2] = fmaf(rv0, w.z, acc[0][2]); acc[0][3] = fmaf(rv0, w.w, acc[0][3]);
            acc[1][0] = fmaf(rv1, w.x, acc[1][0]); acc[1][1] = fmaf(rv1, w.y, acc[1][1]);
            acc[1][2] = fmaf(rv1, w.z, acc[1][2]); acc[1][3] = fmaf(rv1, w.w, acc[1][3]);
            acc[2][0] = fmaf(rv2, w.x, acc[2][0]); acc[2][1] = fmaf(rv2, w.y, acc[2][1]);
            acc[2][2] = fmaf(rv2, w.z, acc[2][2]); acc[2][3] = fmaf(rv2, w.w, acc[2][3]);
            acc[3][0] = fmaf(rv3, w.x, acc[3][0]); acc[3][1] = fmaf(rv3, w.y, acc[3][1]);
            acc[3][2] = fmaf(rv3, w.z, acc[3][2]); acc[3][3] = fmaf(rv3, w.w, acc[3][3]);
        }
    }
    float4* out4 = (float4*)out;
    if (jg < 16) {
#pragma unroll
        for (int r = 0; r < 4; ++r) {
            out4[(size_t)(base + r0 + r) * 16 + jg] =
                make_float4(acc[r][0], acc[r][1], acc[r][2], acc[r][3]);
        }
    } else {
#pragma unroll
        for (int r = 0; r < 4; ++r) {
            float4 o = make_float4(fminf(acc[r][0], 10.0f), fminf(acc[r][1], 10.0f),
                                   fminf(acc[r][2], 10.0f), fminf(acc[r][3], 10.0f));
            out4[(size_t)NN * 16 + (size_t)(base + r0 + r) * 16 + (jg - 16)] = o;
        }
    }
}

// ---------------- decoder loss: 4 edges per 16-lane group (8 gathers in flight) ----------------
__global__ __launch_bounds__(256) void k_loss(const int* __restrict__ pos,
                                              const int* __restrict__ neg,
                                              const float4* __restrict__ z4,
                                              float* __restrict__ accum) {
    int t = blockIdx.x * blockDim.x + threadIdx.x;
    int grp = t >> 4, q = t & 15;
    int e0 = grp * 4;                          // 4 consecutive ids in [0, 2*NP)
    bool isNeg = e0 >= NP;                     // uniform within group (NP % 4 == 0)
    const int* idx = isNeg ? neg : pos;
    int eb = isNeg ? e0 - NP : e0;
    int a0 = idx[eb + 0], b0 = idx[NP + eb + 0];
    int a1 = idx[eb + 1], b1 = idx[NP + eb + 1];
    int a2 = idx[eb + 2], b2 = idx[NP + eb + 2];
    int a3 = idx[eb + 3], b3 = idx[NP + eb + 3];
    float4 va0 = z4[(size_t)a0 * 16 + q], vb0 = z4[(size_t)b0 * 16 + q];
    float4 va1 = z4[(size_t)a1 * 16 + q], vb1 = z4[(size_t)b1 * 16 + q];
    float4 va2 = z4[(size_t)a2 * 16 + q], vb2 = z4[(size_t)b2 * 16 + q];
    float4 va3 = z4[(size_t)a3 * 16 + q], vb3 = z4[(size_t)b3 * 16 + q];
    float d0 = va0.x * vb0.x + va0.y * vb0.y + va0.z * vb0.z + va0.w * vb0.w;
    float d1 = va1.x * vb1.x + va1.y * vb1.y + va1.z * vb1.z + va1.w * vb1.w;
    float d2 = va2.x * vb2.x + va2.y * vb2.y + va2.z * vb2.z + va2.w * vb2.w;
    float d3 = va3.x * vb3.x + va3.y * vb3.y + va3.z * vb3.z + va3.w * vb3.w;
#pragma unroll
    for (int off = 1; off < 16; off <<= 1) {
        d0 += __shfl_xor(d0, off);
        d1 += __shfl_xor(d1, off);
        d2 += __shfl_xor(d2, off);
        d3 += __shfl_xor(d3, off);
    }
    __shared__ float bsum[2];
    if (threadIdx.x < 2) bsum[threadIdx.x] = 0.0f;
    __syncthreads();
    if (q == 0) {
        float term;
        if (isNeg) {
            term = logf(1.0f - 1.0f / (1.0f + expf(-d0)) + 1e-15f)
                 + logf(1.0f - 1.0f / (1.0f + expf(-d1)) + 1e-15f)
                 + logf(1.0f - 1.0f / (1.0f + expf(-d2)) + 1e-15f)
                 + logf(1.0f - 1.0f / (1.0f + expf(-d3)) + 1e-15f);
        } else {
            term = logf(1.0f / (1.0f + expf(-d0)) + 1e-15f)
                 + logf(1.0f / (1.0f + expf(-d1)) + 1e-15f)
                 + logf(1.0f / (1.0f + expf(-d2)) + 1e-15f)
                 + logf(1.0f / (1.0f + expf(-d3)) + 1e-15f);
        }
        atomicAdd(&bsum[isNeg ? 1 : 0], term);
    }
    __syncthreads();
    if (threadIdx.x < 2) atomicAdd(&accum[threadIdx.x], bsum[threadIdx.x]);
}

__global__ void k_fin(const float* __restrict__ accum, float* __restrict__ out) {
    out[(size_t)NN * 128] = -(accum[0] + accum[1]) * (1.0f / (float)NP);
}

extern "C" void kernel_launch(void* const* d_in, const int* in_sizes, int n_in,
                              void* d_out, int out_size, void* d_ws, size_t ws_size,
                              hipStream_t stream) {
    const float* emb = (const float*)d_in[0];
    const int*   ei  = (const int*)d_in[1];
    const float* W1  = (const float*)d_in[2];
    const float* b1  = (const float*)d_in[3];
    const float* Wmu = (const float*)d_in[4];
    const float* bmu = (const float*)d_in[5];
    const float* Wls = (const float*)d_in[6];
    const float* bls = (const float*)d_in[7];
    const int*   pos = (const int*)d_in[8];
    const int*   neg = (const int*)d_in[9];
    float* out = (float*)d_out;

    char* ws = (char*)d_ws;
    float* dinv   = (float*)(ws);                        // 400 KB
    int*   deg    = (int*)  (ws + (512 << 10));          // 400 KB
    int*   cnt    = (int*)  (ws + (1024 << 10));         // 400 KB
    int*   rowptr = (int*)  (ws + (1536 << 10));         // 400 KB + 4
    float* accum  = (float*)(ws + (2048 << 10));         // 8 B
    int2*  edges  = (int2*) (ws + (2048 << 10) + 256);   // 12.8 MB
    float* agg    = (float*)(ws + (16384 << 10));        // 51.2 MB (aggE then aggH)
    float* aggE   = agg;
    float* aggH   = agg;                                 // reuse after aggE dead
    float* h      = out;                                 // N*128 floats staged in d_out

    hipMemsetAsync(deg, 0, NN * sizeof(int), stream);
    hipMemsetAsync(cnt, 0, NN * sizeof(int), stream);
    hipMemsetAsync(accum, 0, 2 * sizeof(float), stream);

    k_deg    <<<(NE + 255) / 256, 256, 0, stream>>>(ei, deg);
    k_dinv   <<<(NN + 255) / 256, 256, 0, stream>>>(deg, dinv);
    k_scan   <<<1, 1024, 0, stream>>>(deg, rowptr);
    k_scatter<<<(NE + 255) / 256, 256, 0, stream>>>(ei, dinv, rowptr, cnt, edges);

    k_aggE<<<(NN * 16) / 256, 256, 0, stream>>>((const float4*)emb, dinv, rowptr, edges,
                                                (float4*)aggE);
    k_h<<<NN / 32, 256, 0, stream>>>(aggE, (const float4*)W1, b1, (float4*)h);

    k_aggH<<<(NN * 32) / 256, 256, 0, stream>>>((const float4*)h, dinv, rowptr, edges,
                                                (float4*)aggH);
    k_out<<<NN / 32, 256, 0, stream>>>(aggH, (const float4*)Wmu, bmu,
                                       (const float4*)Wls, bls, out);

    k_loss<<<(2 * NP * 16) / (256 * 4), 256, 0, stream>>>(pos, neg, (const float4*)out, accum);
    k_fin<<<1, 1, 0, stream>>>(accum, out);
}

// Round 5
// 422.151 us; speedup vs baseline: 10.8220x; 1.2057x over previous
//
#include <hip/hip_runtime.h>
#include <hip/hip_bf16.h>
#include <hip/hip_fp16.h>

#define NN 100000      // nodes
#define NE 1600000     // edges
#define NP 100000      // pos/neg label edges
// EMB=64, HID=128, OUT=64

// ---------------- fp16 helpers ----------------
__device__ __forceinline__ void h8_to_f(const uint4 u, float* f) {
    const __half2* hp = (const __half2*)&u;
    float2 t0 = __half22float2(hp[0]), t1 = __half22float2(hp[1]);
    float2 t2 = __half22float2(hp[2]), t3 = __half22float2(hp[3]);
    f[0] = t0.x; f[1] = t0.y; f[2] = t1.x; f[3] = t1.y;
    f[4] = t2.x; f[5] = t2.y; f[6] = t3.x; f[7] = t3.y;
}

__device__ __forceinline__ void fma8(const uint4 u, float w, float* acc) {
    float f[8]; h8_to_f(u, f);
#pragma unroll
    for (int i = 0; i < 8; ++i) acc[i] = fmaf(f[i], w, acc[i]);
}

__device__ __forceinline__ uint4 f_to_h8(const float* f) {
    union { __half2 h[4]; uint4 u; } pk;
    pk.h[0] = __floats2half2_rn(f[0], f[1]);
    pk.h[1] = __floats2half2_rn(f[2], f[3]);
    pk.h[2] = __floats2half2_rn(f[4], f[5]);
    pk.h[3] = __floats2half2_rn(f[6], f[7]);
    return pk.u;
}

// ---------------- degree ----------------
__global__ void k_deg(const int* __restrict__ ei, int* __restrict__ deg) {
    int e = blockIdx.x * blockDim.x + threadIdx.x;
    if (e < NE) atomicAdd(&deg[ei[NE + e]], 1);
}

__global__ void k_dinv(const int* __restrict__ deg, float* __restrict__ dinv) {
    int i = blockIdx.x * blockDim.x + threadIdx.x;
    if (i < NN) dinv[i] = rsqrtf((float)deg[i] + 1.0f);
}

// ---------------- emb -> fp16 table ----------------
__global__ void k_cvt(const float4* __restrict__ in4, uint4* __restrict__ out) {
    int t = blockIdx.x * blockDim.x + threadIdx.x;   // NN*8 threads, 8 floats each
    if (t >= NN * 8) return;
    float4 a = in4[t * 2], b = in4[t * 2 + 1];
    float f[8] = {a.x, a.y, a.z, a.w, b.x, b.y, b.z, b.w};
    out[t] = f_to_h8(f);
}

// ---------------- exclusive scan over deg -> rowptr (single workgroup, int4) ----------------
__global__ __launch_bounds__(1024) void k_scan(const int* __restrict__ deg,
                                               int* __restrict__ rowptr) {
    __shared__ int part[1024];
    int t = threadIdx.x;
    int lo = t * 100;                       // 1000 active threads, 100 each
    int s = 0;
    if (lo < NN) {
        const int4* d4 = (const int4*)(deg + lo);
#pragma unroll
        for (int i = 0; i < 25; ++i) { int4 d = d4[i]; s += d.x + d.y + d.z + d.w; }
    }
    part[t] = s;
    __syncthreads();
    for (int off = 1; off < 1024; off <<= 1) {
        int add = (t >= off) ? part[t - off] : 0;
        __syncthreads();
        part[t] += add;
        __syncthreads();
    }
    int run = part[t] - s;                  // exclusive prefix
    if (lo < NN) {
        const int4* d4 = (const int4*)(deg + lo);
        int4* r4 = (int4*)(rowptr + lo);
#pragma unroll
        for (int i = 0; i < 25; ++i) {
            int4 d = d4[i];
            r4[i] = make_int4(run, run + d.x, run + d.x + d.y, run + d.x + d.y + d.z);
            run += d.x + d.y + d.z + d.w;
        }
        if (t == 999) rowptr[NN] = run;
    }
}

// ---------------- CSR scatter: edges grouped by dst ----------------
__global__ void k_scatter(const int* __restrict__ ei, const float* __restrict__ dinv,
                          const int* __restrict__ rowptr, int* __restrict__ cnt,
                          int2* __restrict__ edges) {
    int e = blockIdx.x * blockDim.x + threadIdx.x;
    if (e >= NE) return;
    int s = ei[e], d = ei[NE + e];
    int pos = rowptr[d] + atomicAdd(&cnt[d], 1);
    edges[pos] = make_int2(s, __float_as_int(dinv[s]));
}

// ---------------- gather-aggregate, 64 feats fp16 in / fp32 out: 8 lanes per row ----------------
__global__ __launch_bounds__(256) void k_aggE(const uint4* __restrict__ x16,
                                              const float* __restrict__ dinv,
                                              const int* __restrict__ rowptr,
                                              const int2* __restrict__ edges,
                                              float4* __restrict__ agg4) {
    int t = blockIdx.x * blockDim.x + threadIdx.x;   // grid = NN*8 exactly
    int r = t >> 3, q = t & 7;
    float dr = dinv[r];
    float acc[8];
    {
        float f[8]; h8_to_f(x16[(size_t)r * 8 + q], f);
        float sc = dr * dr;
#pragma unroll
        for (int i = 0; i < 8; ++i) acc[i] = f[i] * sc;
    }
    int j = rowptr[r], j1 = rowptr[r + 1];
    for (; j + 8 <= j1; j += 8) {
        int2 e[8]; uint4 v[8];
#pragma unroll
        for (int i = 0; i < 8; ++i) e[i] = edges[j + i];
#pragma unroll
        for (int i = 0; i < 8; ++i) v[i] = x16[(size_t)e[i].x * 8 + q];
#pragma unroll
        for (int i = 0; i < 8; ++i) fma8(v[i], __int_as_float(e[i].y) * dr, acc);
    }
    if (j + 4 <= j1) {
        int2 e[4]; uint4 v[4];
#pragma unroll
        for (int i = 0; i < 4; ++i) e[i] = edges[j + i];
#pragma unroll
        for (int i = 0; i < 4; ++i) v[i] = x16[(size_t)e[i].x * 8 + q];
#pragma unroll
        for (int i = 0; i < 4; ++i) fma8(v[i], __int_as_float(e[i].y) * dr, acc);
        j += 4;
    }
    for (; j < j1; ++j) {
        int2 e = edges[j];
        fma8(x16[(size_t)e.x * 8 + q], __int_as_float(e.y) * dr, acc);
    }
    size_t o = (size_t)r * 16 + q * 2;
    agg4[o]     = make_float4(acc[0], acc[1], acc[2], acc[3]);
    agg4[o + 1] = make_float4(acc[4], acc[5], acc[6], acc[7]);
}

// ---------------- gather-aggregate, 128 feats fp16 in / fp16 out: 16 lanes per row ----------------
__global__ __launch_bounds__(256) void k_aggH(const uint4* __restrict__ x16,
                                              const float* __restrict__ dinv,
                                              const int* __restrict__ rowptr,
                                              const int2* __restrict__ edges,
                                              uint4* __restrict__ aggH16) {
    int t = blockIdx.x * blockDim.x + threadIdx.x;   // grid = NN*16 exactly
    int r = t >> 4, q = t & 15;
    float dr = dinv[r];
    float acc[8];
    {
        float f[8]; h8_to_f(x16[(size_t)r * 16 + q], f);
        float sc = dr * dr;
#pragma unroll
        for (int i = 0; i < 8; ++i) acc[i] = f[i] * sc;
    }
    int j = rowptr[r], j1 = rowptr[r + 1];
    for (; j + 8 <= j1; j += 8) {
        int2 e[8]; uint4 v[8];
#pragma unroll
        for (int i = 0; i < 8; ++i) e[i] = edges[j + i];
#pragma unroll
        for (int i = 0; i < 8; ++i) v[i] = x16[(size_t)e[i].x * 16 + q];
#pragma unroll
        for (int i = 0; i < 8; ++i) fma8(v[i], __int_as_float(e[i].y) * dr, acc);
    }
    if (j + 4 <= j1) {
        int2 e[4]; uint4 v[4];
#pragma unroll
        for (int i = 0; i < 4; ++i) e[i] = edges[j + i];
#pragma unroll
        for (int i = 0; i < 4; ++i) v[i] = x16[(size_t)e[i].x * 16 + q];
#pragma unroll
        for (int i = 0; i < 4; ++i) fma8(v[i], __int_as_float(e[i].y) * dr, acc);
        j += 4;
    }
    for (; j < j1; ++j) {
        int2 e = edges[j];
        fma8(x16[(size_t)e.x * 16 + q], __int_as_float(e.y) * dr, acc);
    }
    aggH16[(size_t)r * 16 + q] = f_to_h8(acc);
}

// ---------------- h = relu(aggE @ W1 + b1), [N,64]x[64,128], 4x4 register tile ----------------
__global__ __launch_bounds__(256) void k_h(const float* __restrict__ aggE,
                                           const float4* __restrict__ W1_4,  // [64][32] f4
                                           const float* __restrict__ b1,
                                           uint2* __restrict__ h16) {
    __shared__ float4 w4[64 * 32];     // w4[k*32+jg] = W1[k][4jg..4jg+3]
    __shared__ float rows[32 * 65];    // padded
    int t = threadIdx.x;
    int base = blockIdx.x * 32;
#pragma unroll
    for (int i = 0; i < 8; ++i) w4[t + i * 256] = W1_4[t + i * 256];
#pragma unroll
    for (int i = 0; i < 8; ++i) {
        int idx = t + i * 256;
        int r = idx >> 6, kk = idx & 63;
        rows[r * 65 + kk] = aggE[(size_t)(base + r) * 64 + kk];
    }
    __syncthreads();
    int rg = t >> 5, jg = t & 31;
    int r0 = rg * 4;
    float4 bias = ((const float4*)b1)[jg];
    float acc[4][4];
#pragma unroll
    for (int r = 0; r < 4; ++r) {
        acc[r][0] = bias.x; acc[r][1] = bias.y; acc[r][2] = bias.z; acc[r][3] = bias.w;
    }
#pragma unroll 8
    for (int k = 0; k < 64; ++k) {
        float4 w = w4[k * 32 + jg];
        float rv0 = rows[(r0 + 0) * 65 + k];
        float rv1 = rows[(r0 + 1) * 65 + k];
        float rv2 = rows[(r0 + 2) * 65 + k];
        float rv3 = rows[(r0 + 3) * 65 + k];
        acc[0][0] = fmaf(rv0, w.x, acc[0][0]); acc[0][1] = fmaf(rv0, w.y, acc[0][1]);
        acc[0][2] = fmaf(rv0, w.z, acc[0][2]); acc[0][3] = fmaf(rv0, w.w, acc[0][3]);
        acc[1][0] = fmaf(rv1, w.x, acc[1][0]); acc[1][1] = fmaf(rv1, w.y, acc[1][1]);
        acc[1][2] = fmaf(rv1, w.z, acc[1][2]); acc[1][3] = fmaf(rv1, w.w, acc[1][3]);
        acc[2][0] = fmaf(rv2, w.x, acc[2][0]); acc[2][1] = fmaf(rv2, w.y, acc[2][1]);
        acc[2][2] = fmaf(rv2, w.z, acc[2][2]); acc[2][3] = fmaf(rv2, w.w, acc[2][3]);
        acc[3][0] = fmaf(rv3, w.x, acc[3][0]); acc[3][1] = fmaf(rv3, w.y, acc[3][1]);
        acc[3][2] = fmaf(rv3, w.z, acc[3][2]); acc[3][3] = fmaf(rv3, w.w, acc[3][3]);
    }
#pragma unroll
    for (int r = 0; r < 4; ++r) {
        union { __half2 h[2]; uint2 u; } pk;
        pk.h[0] = __floats2half2_rn(fmaxf(acc[r][0], 0.0f), fmaxf(acc[r][1], 0.0f));
        pk.h[1] = __floats2half2_rn(fmaxf(acc[r][2], 0.0f), fmaxf(acc[r][3], 0.0f));
        h16[(size_t)(base + r0 + r) * 32 + jg] = pk.u;
    }
}

// ---------------- mu/logstd = aggH @ [Wmu|Wls] + b, fp16 aggH in, 4x4 tile ----------------
__global__ __launch_bounds__(256) void k_out(const uint4* __restrict__ aggH16,
                                             const float4* __restrict__ Wmu4, // [128][16] f4
                                             const float* __restrict__ bmu,
                                             const float4* __restrict__ Wls4, // [128][16] f4
                                             const float* __restrict__ bls,
                                             float* __restrict__ out) {
    __shared__ float4 w4[64 * 32];     // w4[kk*32+jj] = W[kh*64+kk][4jj..4jj+3] combined
    __shared__ float rows[32 * 129];   // padded, full 128 feats
    int t = threadIdx.x;
    int base = blockIdx.x * 32;
#pragma unroll
    for (int i = 0; i < 2; ++i) {
        int idx = t + i * 256;          // 512 uint4 total = 32 rows x 16
        int r = idx >> 4, c = idx & 15;
        float f[8]; h8_to_f(aggH16[(size_t)(base + r) * 16 + c], f);
#pragma unroll
        for (int kk = 0; kk < 8; ++kk) rows[r * 129 + c * 8 + kk] = f[kk];
    }
    int rg = t >> 5, jg = t & 31;
    int r0 = rg * 4;
    float4 bias = (jg < 16) ? ((const float4*)bmu)[jg] : ((const float4*)bls)[jg - 16];
    float acc[4][4];
#pragma unroll
    for (int r = 0; r < 4; ++r) {
        acc[r][0] = bias.x; acc[r][1] = bias.y; acc[r][2] = bias.z; acc[r][3] = bias.w;
    }
    for (int kh = 0; kh < 2; ++kh) {
        if (kh) __syncthreads();      // all waves done reading previous w4
#pragma unroll
        for (int i = 0; i < 8; ++i) {
            int idx = t + i * 256;
            int jj = idx & 31, kk = idx >> 5;
            int k = kh * 64 + kk;
            w4[idx] = (jj < 16) ? Wmu4[k * 16 + jj] : Wls4[k * 16 + (jj - 16)];
        }
        __syncthreads();
#pragma unroll 8
        for (int kk = 0; kk < 64; ++kk) {
            int k = kh * 64 + kk;
            float4 w = w4[kk * 32 + jg];
            float rv0 = rows[(r0 + 0) * 129 + k];
            float rv1 = rows[(r0 + 1) * 129 + k];
            float rv2 = rows[(r0 + 2) * 129 + k];
            float rv3 = rows[(r0 + 3) * 129 + k];
            acc[0][0] = fmaf(rv0, w.x, acc[0][0]); acc[0][1] = fmaf(rv0, w.y, acc[0][1]);
            acc[0][2] = fmaf(rv0, w.z, acc[0][2]); acc[0][3] = fmaf(rv0, w.w, acc[0][3]);
            acc[1][0] = fmaf(rv1, w.x, acc[1][0]); acc[1][1] = fmaf(rv1, w.y, acc[1][1]);
            acc[1][2] = fmaf(rv1, w.z, acc[1][2]); acc[1][3] = fmaf(rv1, w.w, acc[1][3]);
            acc[2][0] = fmaf(rv2, w.x, acc[2][0]); acc[2][1] = fmaf(rv2, w.y, acc[2][1]);
            acc[2][2] = fmaf(rv2, w.z, acc[2][2]); acc[2][3] = fmaf(rv2, w.w, acc[2][3]);
            acc[3][0] = fmaf(rv3, w.x, acc[3][0]); acc[3][1] = fmaf(rv3, w.y, acc[3][1]);
            acc[3][2] = fmaf(rv3, w.z, acc[3][2]); acc[3][3] = fmaf(rv3, w.w, acc[3][3]);
        }
    }
    float4* out4 = (float4*)out;
    if (jg < 16) {
#pragma unroll
        for (int r = 0; r < 4; ++r) {
            out4[(size_t)(base + r0 + r) * 16 + jg] =
                make_float4(acc[r][0], acc[r][1], acc[r][2], acc[r][3]);
        }
    } else {
#pragma unroll
        for (int r = 0; r < 4; ++r) {
            float4 o = make_float4(fminf(acc[r][0], 10.0f), fminf(acc[r][1], 10.0f),
                                   fminf(acc[r][2], 10.0f), fminf(acc[r][3], 10.0f));
            out4[(size_t)NN * 16 + (size_t)(base + r0 + r) * 16 + (jg - 16)] = o;
        }
    }
}

// ---------------- decoder loss: 4 edges per 16-lane group (8 gathers in flight) ----------------
__global__ __launch_bounds__(256) void k_loss(const int* __restrict__ pos,
                                              const int* __restrict__ neg,
                                              const float4* __restrict__ z4,
                                              float* __restrict__ accum) {
    int t = blockIdx.x * blockDim.x + threadIdx.x;
    int grp = t >> 4, q = t & 15;
    int e0 = grp * 4;                          // 4 consecutive ids in [0, 2*NP)
    bool isNeg = e0 >= NP;                     // uniform within group (NP % 4 == 0)
    const int* idx = isNeg ? neg : pos;
    int eb = isNeg ? e0 - NP : e0;
    int a0 = idx[eb + 0], b0 = idx[NP + eb + 0];
    int a1 = idx[eb + 1], b1 = idx[NP + eb + 1];
    int a2 = idx[eb + 2], b2 = idx[NP + eb + 2];
    int a3 = idx[eb + 3], b3 = idx[NP + eb + 3];
    float4 va0 = z4[(size_t)a0 * 16 + q], vb0 = z4[(size_t)b0 * 16 + q];
    float4 va1 = z4[(size_t)a1 * 16 + q], vb1 = z4[(size_t)b1 * 16 + q];
    float4 va2 = z4[(size_t)a2 * 16 + q], vb2 = z4[(size_t)b2 * 16 + q];
    float4 va3 = z4[(size_t)a3 * 16 + q], vb3 = z4[(size_t)b3 * 16 + q];
    float d0 = va0.x * vb0.x + va0.y * vb0.y + va0.z * vb0.z + va0.w * vb0.w;
    float d1 = va1.x * vb1.x + va1.y * vb1.y + va1.z * vb1.z + va1.w * vb1.w;
    float d2 = va2.x * vb2.x + va2.y * vb2.y + va2.z * vb2.z + va2.w * vb2.w;
    float d3 = va3.x * vb3.x + va3.y * vb3.y + va3.z * vb3.z + va3.w * vb3.w;
#pragma unroll
    for (int off = 1; off < 16; off <<= 1) {
        d0 += __shfl_xor(d0, off);
        d1 += __shfl_xor(d1, off);
        d2 += __shfl_xor(d2, off);
        d3 += __shfl_xor(d3, off);
    }
    __shared__ float bsum[2];
    if (threadIdx.x < 2) bsum[threadIdx.x] = 0.0f;
    __syncthreads();
    if (q == 0) {
        float term;
        if (isNeg) {
            term = logf(1.0f - 1.0f / (1.0f + expf(-d0)) + 1e-15f)
                 + logf(1.0f - 1.0f / (1.0f + expf(-d1)) + 1e-15f)
                 + logf(1.0f - 1.0f / (1.0f + expf(-d2)) + 1e-15f)
                 + logf(1.0f - 1.0f / (1.0f + expf(-d3)) + 1e-15f);
        } else {
            term = logf(1.0f / (1.0f + expf(-d0)) + 1e-15f)
                 + logf(1.0f / (1.0f + expf(-d1)) + 1e-15f)
                 + logf(1.0f / (1.0f + expf(-d2)) + 1e-15f)
                 + logf(1.0f / (1.0f + expf(-d3)) + 1e-15f);
        }
        atomicAdd(&bsum[isNeg ? 1 : 0], term);
    }
    __syncthreads();
    if (threadIdx.x < 2) atomicAdd(&accum[threadIdx.x], bsum[threadIdx.x]);
}

__global__ void k_fin(const float* __restrict__ accum, float* __restrict__ out) {
    out[(size_t)NN * 128] = -(accum[0] + accum[1]) * (1.0f / (float)NP);
}

extern "C" void kernel_launch(void* const* d_in, const int* in_sizes, int n_in,
                              void* d_out, int out_size, void* d_ws, size_t ws_size,
                              hipStream_t stream) {
    const float* emb = (const float*)d_in[0];
    const int*   ei  = (const int*)d_in[1];
    const float* W1  = (const float*)d_in[2];
    const float* b1  = (const float*)d_in[3];
    const float* Wmu = (const float*)d_in[4];
    const float* bmu = (const float*)d_in[5];
    const float* Wls = (const float*)d_in[6];
    const float* bls = (const float*)d_in[7];
    const int*   pos = (const int*)d_in[8];
    const int*   neg = (const int*)d_in[9];
    float* out = (float*)d_out;

    char* ws = (char*)d_ws;
    // small buffers
    float* dinv   = (float*)(ws);                        // 400 KB
    int*   deg    = (int*)  (ws + (512 << 10));          // 400 KB
    int*   cnt    = (int*)  (ws + (1024 << 10));         // 400 KB
    int*   rowptr = (int*)  (ws + (1536 << 10));         // 400 KB + 4
    float* accum  = (float*)(ws + (2048 << 10));         // 8 B
    // big buffers (all offsets 256B-aligned)
    const size_t OFF_EDGES = (2048 << 10) + 256;                 // 12.8 MB
    const size_t OFF_H16   = OFF_EDGES + (size_t)NE * 8;         // 25.6 MB
    const size_t OFF_E16   = OFF_H16 + (size_t)NN * 128 * 2;     // 12.8 MB (emb16; aggH16 reuses)
    int2*  edges  = (int2*)(ws + OFF_EDGES);
    uint2* h16    = (uint2*)(ws + OFF_H16);
    uint4* emb16  = (uint4*)(ws + OFF_E16);
    uint4* aggH16 = (uint4*)(ws + OFF_E16);              // emb16 dead by k_aggH
    float* aggE   = out;                                 // 25.6 MB staged in d_out (dead region)

    hipMemsetAsync(deg, 0, NN * sizeof(int), stream);
    hipMemsetAsync(cnt, 0, NN * sizeof(int), stream);
    hipMemsetAsync(accum, 0, 2 * sizeof(float), stream);

    k_cvt    <<<(NN * 8 + 255) / 256, 256, 0, stream>>>((const float4*)emb, emb16);
    k_deg    <<<(NE + 255) / 256, 256, 0, stream>>>(ei, deg);
    k_dinv   <<<(NN + 255) / 256, 256, 0, stream>>>(deg, dinv);
    k_scan   <<<1, 1024, 0, stream>>>(deg, rowptr);
    k_scatter<<<(NE + 255) / 256, 256, 0, stream>>>(ei, dinv, rowptr, cnt, edges);

    k_aggE<<<(NN * 8) / 256, 256, 0, stream>>>(emb16, dinv, rowptr, edges, (float4*)aggE);
    k_h<<<NN / 32, 256, 0, stream>>>(aggE, (const float4*)W1, b1, h16);

    k_aggH<<<(NN * 16) / 256, 256, 0, stream>>>((const uint4*)h16, dinv, rowptr, edges, aggH16);
    k_out<<<NN / 32, 256, 0, stream>>>(aggH16, (const float4*)Wmu, bmu,
                                       (const float4*)Wls, bls, out);

    k_loss<<<(2 * NP * 16) / (256 * 4), 256, 0, stream>>>(pos, neg, (const float4*)out, accum);
    k_fin<<<1, 1, 0, stream>>>(accum, out);
}

// Round 7
// 418.944 us; speedup vs baseline: 10.9049x; 1.0077x over previous
//
#include <hip/hip_runtime.h>
#include <hip/hip_bf16.h>
#include <hip/hip_fp16.h>

#define NN 100000      // nodes
#define NE 1600000     // edges
#define NP 100000      // pos/neg label edges
// EMB=64, HID=128, OUT=64

// ---------------- fp16 helpers ----------------
__device__ __forceinline__ void h8_to_f(const uint4 u, float* f) {
    const __half2* hp = (const __half2*)&u;
    float2 t0 = __half22float2(hp[0]), t1 = __half22float2(hp[1]);
    float2 t2 = __half22float2(hp[2]), t3 = __half22float2(hp[3]);
    f[0] = t0.x; f[1] = t0.y; f[2] = t1.x; f[3] = t1.y;
    f[4] = t2.x; f[5] = t2.y; f[6] = t3.x; f[7] = t3.y;
}

__device__ __forceinline__ void fma8(const uint4 u, float w, float* acc) {
    float f[8]; h8_to_f(u, f);
#pragma unroll
    for (int i = 0; i < 8; ++i) acc[i] = fmaf(f[i], w, acc[i]);
}

__device__ __forceinline__ uint4 f_to_h8(const float* f) {
    union { __half2 h[4]; uint4 u; } pk;
    pk.h[0] = __floats2half2_rn(f[0], f[1]);
    pk.h[1] = __floats2half2_rn(f[2], f[3]);
    pk.h[2] = __floats2half2_rn(f[4], f[5]);
    pk.h[3] = __floats2half2_rn(f[6], f[7]);
    return pk.u;
}

__device__ __forceinline__ float dot4h(uint2 a, uint2 b) {
    const __half2* ah = (const __half2*)&a;
    const __half2* bh = (const __half2*)&b;
    float2 a0 = __half22float2(ah[0]), a1 = __half22float2(ah[1]);
    float2 b0 = __half22float2(bh[0]), b1 = __half22float2(bh[1]);
    return a0.x * b0.x + a0.y * b0.y + a1.x * b1.x + a1.y * b1.y;
}

// ---------------- degree ----------------
__global__ void k_deg(const int* __restrict__ ei, int* __restrict__ deg) {
    int e = blockIdx.x * blockDim.x + threadIdx.x;
    if (e < NE) atomicAdd(&deg[ei[NE + e]], 1);
}

__global__ void k_dinv(const int* __restrict__ deg, float* __restrict__ dinv) {
    int i = blockIdx.x * blockDim.x + threadIdx.x;
    if (i < NN) dinv[i] = rsqrtf((float)deg[i] + 1.0f);
}

// ---------------- emb -> fp16 table ----------------
__global__ void k_cvt(const float4* __restrict__ in4, uint4* __restrict__ out) {
    int t = blockIdx.x * blockDim.x + threadIdx.x;   // NN*8 threads, 8 floats each
    if (t >= NN * 8) return;
    float4 a = in4[t * 2], b = in4[t * 2 + 1];
    float f[8] = {a.x, a.y, a.z, a.w, b.x, b.y, b.z, b.w};
    out[t] = f_to_h8(f);
}

// ---------------- exclusive scan over deg -> rowptr (single workgroup, int4) ----------------
__global__ __launch_bounds__(1024) void k_scan(const int* __restrict__ deg,
                                               int* __restrict__ rowptr) {
    __shared__ int part[1024];
    int t = threadIdx.x;
    int lo = t * 100;                       // 1000 active threads, 100 each
    int s = 0;
    if (lo < NN) {
        const int4* d4 = (const int4*)(deg + lo);
#pragma unroll
        for (int i = 0; i < 25; ++i) { int4 d = d4[i]; s += d.x + d.y + d.z + d.w; }
    }
    part[t] = s;
    __syncthreads();
    for (int off = 1; off < 1024; off <<= 1) {
        int add = (t >= off) ? part[t - off] : 0;
        __syncthreads();
        part[t] += add;
        __syncthreads();
    }
    int run = part[t] - s;                  // exclusive prefix
    if (lo < NN) {
        const int4* d4 = (const int4*)(deg + lo);
        int4* r4 = (int4*)(rowptr + lo);
#pragma unroll
        for (int i = 0; i < 25; ++i) {
            int4 d = d4[i];
            r4[i] = make_int4(run, run + d.x, run + d.x + d.y, run + d.x + d.y + d.z);
            run += d.x + d.y + d.z + d.w;
        }
        if (t == 999) rowptr[NN] = run;
    }
}

// ---------------- CSR scatter, XCD-partitioned by dst range ----------------
// grid = SCHUNKS*8 blocks. Block b: chunk c = b>>3, dst-range r = b&7.
// All writers of range r share (heuristically) one XCD -> CSR lines accumulate
// in that XCD's L2 and write back once instead of ~8 partial writebacks.
// Correctness does not depend on the XCD mapping (each edge written exactly once).
#define SCHUNKS 256
#define CHSZ (NE / SCHUNKS)     // 6250
__global__ __launch_bounds__(256) void k_scatter8(const int* __restrict__ ei,
                                                  const float* __restrict__ dinv,
                                                  const int* __restrict__ rowptr,
                                                  int* __restrict__ cnt,
                                                  int2* __restrict__ edges) {
    int b = blockIdx.x;
    int r = b & 7, c = b >> 3;
    int lo = r * (NN / 8), hi = lo + (NN / 8);
    int e0 = c * CHSZ;
    for (int i = threadIdx.x; i < CHSZ; i += 256) {
        int e = e0 + i;
        int d = ei[NE + e];
        int s = ei[e];                       // coalesced; same lines for all 8 range-blocks
        if (d >= lo && d < hi) {
            int p = rowptr[d] + atomicAdd(&cnt[d], 1);
            edges[p] = make_int2(s, __float_as_int(dinv[s]));
        }
    }
}

// ---------------- gather-aggregate, 64 feats fp16 in / fp32 out: 8 lanes per row ----------------
__global__ __launch_bounds__(256) void k_aggE(const uint4* __restrict__ x16,
                                              const float* __restrict__ dinv,
                                              const int* __restrict__ rowptr,
                                              const int2* __restrict__ edges,
                                              float4* __restrict__ agg4) {
    int t = blockIdx.x * blockDim.x + threadIdx.x;   // grid = NN*8 exactly
    int r = t >> 3, q = t & 7;
    float dr = dinv[r];
    float acc[8];
    {
        float f[8]; h8_to_f(x16[(size_t)r * 8 + q], f);
        float sc = dr * dr;
#pragma unroll
        for (int i = 0; i < 8; ++i) acc[i] = f[i] * sc;
    }
    int j = rowptr[r], j1 = rowptr[r + 1];
    for (; j + 8 <= j1; j += 8) {
        int2 e[8]; uint4 v[8];
#pragma unroll
        for (int i = 0; i < 8; ++i) e[i] = edges[j + i];
#pragma unroll
        for (int i = 0; i < 8; ++i) v[i] = x16[(size_t)e[i].x * 8 + q];
#pragma unroll
        for (int i = 0; i < 8; ++i) fma8(v[i], __int_as_float(e[i].y) * dr, acc);
    }
    if (j + 4 <= j1) {
        int2 e[4]; uint4 v[4];
#pragma unroll
        for (int i = 0; i < 4; ++i) e[i] = edges[j + i];
#pragma unroll
        for (int i = 0; i < 4; ++i) v[i] = x16[(size_t)e[i].x * 8 + q];
#pragma unroll
        for (int i = 0; i < 4; ++i) fma8(v[i], __int_as_float(e[i].y) * dr, acc);
        j += 4;
    }
    for (; j < j1; ++j) {
        int2 e = edges[j];
        fma8(x16[(size_t)e.x * 8 + q], __int_as_float(e.y) * dr, acc);
    }
    size_t o = (size_t)r * 16 + q * 2;
    agg4[o]     = make_float4(acc[0], acc[1], acc[2], acc[3]);
    agg4[o + 1] = make_float4(acc[4], acc[5], acc[6], acc[7]);
}

// ---------------- gather-aggregate, 128 feats fp16 in / fp16 out: 16 lanes per row ----------------
__global__ __launch_bounds__(256) void k_aggH(const uint4* __restrict__ x16,
                                              const float* __restrict__ dinv,
                                              const int* __restrict__ rowptr,
                                              const int2* __restrict__ edges,
                                              uint4* __restrict__ aggH16) {
    int t = blockIdx.x * blockDim.x + threadIdx.x;   // grid = NN*16 exactly
    int r = t >> 4, q = t & 15;
    float dr = dinv[r];
    float acc[8];
    {
        float f[8]; h8_to_f(x16[(size_t)r * 16 + q], f);
        float sc = dr * dr;
#pragma unroll
        for (int i = 0; i < 8; ++i) acc[i] = f[i] * sc;
    }
    int j = rowptr[r], j1 = rowptr[r + 1];
    for (; j + 8 <= j1; j += 8) {
        int2 e[8]; uint4 v[8];
#pragma unroll
        for (int i = 0; i < 8; ++i) e[i] = edges[j + i];
#pragma unroll
        for (int i = 0; i < 8; ++i) v[i] = x16[(size_t)e[i].x * 16 + q];
#pragma unroll
        for (int i = 0; i < 8; ++i) fma8(v[i], __int_as_float(e[i].y) * dr, acc);
    }
    if (j + 4 <= j1) {
        int2 e[4]; uint4 v[4];
#pragma unroll
        for (int i = 0; i < 4; ++i) e[i] = edges[j + i];
#pragma unroll
        for (int i = 0; i < 4; ++i) v[i] = x16[(size_t)e[i].x * 16 + q];
#pragma unroll
        for (int i = 0; i < 4; ++i) fma8(v[i], __int_as_float(e[i].y) * dr, acc);
        j += 4;
    }
    for (; j < j1; ++j) {
        int2 e = edges[j];
        fma8(x16[(size_t)e.x * 16 + q], __int_as_float(e.y) * dr, acc);
    }
    aggH16[(size_t)r * 16 + q] = f_to_h8(acc);
}

// ---------------- h = relu(aggE @ W1 + b1), [N,64]x[64,128], 4x4 register tile ----------------
__global__ __launch_bounds__(256) void k_h(const float* __restrict__ aggE,
                                           const float4* __restrict__ W1_4,  // [64][32] f4
                                           const float* __restrict__ b1,
                                           uint2* __restrict__ h16) {
    __shared__ float4 w4[64 * 32];     // w4[k*32+jg] = W1[k][4jg..4jg+3]
    __shared__ float rows[32 * 65];    // padded
    int t = threadIdx.x;
    int base = blockIdx.x * 32;
#pragma unroll
    for (int i = 0; i < 8; ++i) w4[t + i * 256] = W1_4[t + i * 256];
#pragma unroll
    for (int i = 0; i < 8; ++i) {
        int idx = t + i * 256;
        int r = idx >> 6, kk = idx & 63;
        rows[r * 65 + kk] = aggE[(size_t)(base + r) * 64 + kk];
    }
    __syncthreads();
    int rg = t >> 5, jg = t & 31;
    int r0 = rg * 4;
    float4 bias = ((const float4*)b1)[jg];
    float acc[4][4];
#pragma unroll
    for (int r = 0; r < 4; ++r) {
        acc[r][0] = bias.x; acc[r][1] = bias.y; acc[r][2] = bias.z; acc[r][3] = bias.w;
    }
#pragma unroll 8
    for (int k = 0; k < 64; ++k) {
        float4 w = w4[k * 32 + jg];
        float rv0 = rows[(r0 + 0) * 65 + k];
        float rv1 = rows[(r0 + 1) * 65 + k];
        float rv2 = rows[(r0 + 2) * 65 + k];
        float rv3 = rows[(r0 + 3) * 65 + k];
        acc[0][0] = fmaf(rv0, w.x, acc[0][0]); acc[0][1] = fmaf(rv0, w.y, acc[0][1]);
        acc[0][2] = fmaf(rv0, w.z, acc[0][2]); acc[0][3] = fmaf(rv0, w.w, acc[0][3]);
        acc[1][0] = fmaf(rv1, w.x, acc[1][0]); acc[1][1] = fmaf(rv1, w.y, acc[1][1]);
        acc[1][2] = fmaf(rv1, w.z, acc[1][2]); acc[1][3] = fmaf(rv1, w.w, acc[1][3]);
        acc[2][0] = fmaf(rv2, w.x, acc[2][0]); acc[2][1] = fmaf(rv2, w.y, acc[2][1]);
        acc[2][2] = fmaf(rv2, w.z, acc[2][2]); acc[2][3] = fmaf(rv2, w.w, acc[2][3]);
        acc[3][0] = fmaf(rv3, w.x, acc[3][0]); acc[3][1] = fmaf(rv3, w.y, acc[3][1]);
        acc[3][2] = fmaf(rv3, w.z, acc[3][2]); acc[3][3] = fmaf(rv3, w.w, acc[3][3]);
    }
#pragma unroll
    for (int r = 0; r < 4; ++r) {
        union { __half2 h[2]; uint2 u; } pk;
        pk.h[0] = __floats2half2_rn(fmaxf(acc[r][0], 0.0f), fmaxf(acc[r][1], 0.0f));
        pk.h[1] = __floats2half2_rn(fmaxf(acc[r][2], 0.0f), fmaxf(acc[r][3], 0.0f));
        h16[(size_t)(base + r0 + r) * 32 + jg] = pk.u;
    }
}

// ---------------- mu/logstd = aggH @ [Wmu|Wls] + b, fp16 aggH in, 4x4 tile ----------------
// Also emits fp16 copy of z (=mu) for the decoder.
__global__ __launch_bounds__(256) void k_out(const uint4* __restrict__ aggH16,
                                             const float4* __restrict__ Wmu4, // [128][16] f4
                                             const float* __restrict__ bmu,
                                             const float4* __restrict__ Wls4, // [128][16] f4
                                             const float* __restrict__ bls,
                                             float* __restrict__ out,
                                             uint2* __restrict__ z16) {
    __shared__ float4 w4[64 * 32];     // w4[kk*32+jj] = W[kh*64+kk][4jj..4jj+3] combined
    __shared__ float rows[32 * 129];   // padded, full 128 feats
    int t = threadIdx.x;
    int base = blockIdx.x * 32;
#pragma unroll
    for (int i = 0; i < 2; ++i) {
        int idx = t + i * 256;          // 512 uint4 total = 32 rows x 16
        int r = idx >> 4, c = idx & 15;
        float f[8]; h8_to_f(aggH16[(size_t)(base + r) * 16 + c], f);
#pragma unroll
        for (int kk = 0; kk < 8; ++kk) rows[r * 129 + c * 8 + kk] = f[kk];
    }
    int rg = t >> 5, jg = t & 31;
    int r0 = rg * 4;
    float4 bias = (jg < 16) ? ((const float4*)bmu)[jg] : ((const float4*)bls)[jg - 16];
    float acc[4][4];
#pragma unroll
    for (int r = 0; r < 4; ++r) {
        acc[r][0] = bias.x; acc[r][1] = bias.y; acc[r][2] = bias.z; acc[r][3] = bias.w;
    }
    for (int kh = 0; kh < 2; ++kh) {
        if (kh) __syncthreads();      // all waves done reading previous w4
#pragma unroll
        for (int i = 0; i < 8; ++i) {
            int idx = t + i * 256;
            int jj = idx & 31, kk = idx >> 5;
            int k = kh * 64 + kk;
            w4[idx] = (jj < 16) ? Wmu4[k * 16 + jj] : Wls4[k * 16 + (jj - 16)];
        }
        __syncthreads();
#pragma unroll 8
        for (int kk = 0; kk < 64; ++kk) {
            int k = kh * 64 + kk;
            float4 w = w4[kk * 32 + jg];
            float rv0 = rows[(r0 + 0) * 129 + k];
            float rv1 = rows[(r0 + 1) * 129 + k];
            float rv2 = rows[(r0 + 2) * 129 + k];
            float rv3 = rows[(r0 + 3) * 129 + k];
            acc[0][0] = fmaf(rv0, w.x, acc[0][0]); acc[0][1] = fmaf(rv0, w.y, acc[0][1]);
            acc[0][2] = fmaf(rv0, w.z, acc[0][2]); acc[0][3] = fmaf(rv0, w.w, acc[0][3]);
            acc[1][0] = fmaf(rv1, w.x, acc[1][0]); acc[1][1] = fmaf(rv1, w.y, acc[1][1]);
            acc[1][2] = fmaf(rv1, w.z, acc[1][2]); acc[1][3] = fmaf(rv1, w.w, acc[1][3]);
            acc[2][0] = fmaf(rv2, w.x, acc[2][0]); acc[2][1] = fmaf(rv2, w.y, acc[2][1]);
            acc[2][2] = fmaf(rv2, w.z, acc[2][2]); acc[2][3] = fmaf(rv2, w.w, acc[2][3]);
            acc[3][0] = fmaf(rv3, w.x, acc[3][0]); acc[3][1] = fmaf(rv3, w.y, acc[3][1]);
            acc[3][2] = fmaf(rv3, w.z, acc[3][2]); acc[3][3] = fmaf(rv3, w.w, acc[3][3]);
        }
    }
    float4* out4 = (float4*)out;
    if (jg < 16) {
#pragma unroll
        for (int r = 0; r < 4; ++r) {
            out4[(size_t)(base + r0 + r) * 16 + jg] =
                make_float4(acc[r][0], acc[r][1], acc[r][2], acc[r][3]);
            union { __half2 h[2]; uint2 u; } pk;
            pk.h[0] = __floats2half2_rn(acc[r][0], acc[r][1]);
            pk.h[1] = __floats2half2_rn(acc[r][2], acc[r][3]);
            z16[(size_t)(base + r0 + r) * 16 + jg] = pk.u;
        }
    } else {
#pragma unroll
        for (int r = 0; r < 4; ++r) {
            float4 o = make_float4(fminf(acc[r][0], 10.0f), fminf(acc[r][1], 10.0f),
                                   fminf(acc[r][2], 10.0f), fminf(acc[r][3], 10.0f));
            out4[(size_t)NN * 16 + (size_t)(base + r0 + r) * 16 + (jg - 16)] = o;
        }
    }
}

// ---------------- decoder loss: fp16 z, 4 edges per 16-lane group ----------------
__global__ __launch_bounds__(256) void k_loss(const int* __restrict__ pos,
                                              const int* __restrict__ neg,
                                              const uint2* __restrict__ z16,
                                              float* __restrict__ accum) {
    int t = blockIdx.x * blockDim.x + threadIdx.x;
    int grp = t >> 4, q = t & 15;
    int e0 = grp * 4;                          // 4 consecutive ids in [0, 2*NP)
    bool isNeg = e0 >= NP;                     // uniform within group (NP % 4 == 0)
    const int* idx = isNeg ? neg : pos;
    int eb = isNeg ? e0 - NP : e0;
    int a0 = idx[eb + 0], b0 = idx[NP + eb + 0];
    int a1 = idx[eb + 1], b1 = idx[NP + eb + 1];
    int a2 = idx[eb + 2], b2 = idx[NP + eb + 2];
    int a3 = idx[eb + 3], b3 = idx[NP + eb + 3];
    uint2 ua0 = z16[(size_t)a0 * 16 + q], ub0 = z16[(size_t)b0 * 16 + q];
    uint2 ua1 = z16[(size_t)a1 * 16 + q], ub1 = z16[(size_t)b1 * 16 + q];
    uint2 ua2 = z16[(size_t)a2 * 16 + q], ub2 = z16[(size_t)b2 * 16 + q];
    uint2 ua3 = z16[(size_t)a3 * 16 + q], ub3 = z16[(size_t)b3 * 16 + q];
    float d0 = dot4h(ua0, ub0);
    float d1 = dot4h(ua1, ub1);
    float d2 = dot4h(ua2, ub2);
    float d3 = dot4h(ua3, ub3);
#pragma unroll
    for (int off = 1; off < 16; off <<= 1) {
        d0 += __shfl_xor(d0, off);
        d1 += __shfl_xor(d1, off);
        d2 += __shfl_xor(d2, off);
        d3 += __shfl_xor(d3, off);
    }
    __shared__ float bsum[2];
    if (threadIdx.x < 2) bsum[threadIdx.x] = 0.0f;
    __syncthreads();
    if (q == 0) {
        float term;
        if (isNeg) {
            term = logf(1.0f - 1.0f / (1.0f + expf(-d0)) + 1e-15f)
                 + logf(1.0f - 1.0f / (1.0f + expf(-d1)) + 1e-15f)
                 + logf(1.0f - 1.0f / (1.0f + expf(-d2)) + 1e-15f)
                 + logf(1.0f - 1.0f / (1.0f + expf(-d3)) + 1e-15f);
        } else {
            term = logf(1.0f / (1.0f + expf(-d0)) + 1e-15f)
                 + logf(1.0f / (1.0f + expf(-d1)) + 1e-15f)
                 + logf(1.0f / (1.0f + expf(-d2)) + 1e-15f)
                 + logf(1.0f / (1.0f + expf(-d3)) + 1e-15f);
        }
        atomicAdd(&bsum[isNeg ? 1 : 0], term);
    }
    __syncthreads();
    if (threadIdx.x < 2) atomicAdd(&accum[threadIdx.x], bsum[threadIdx.x]);
}

__global__ void k_fin(const float* __restrict__ accum, float* __restrict__ out) {
    out[(size_t)NN * 128] = -(accum[0] + accum[1]) * (1.0f / (float)NP);
}

extern "C" void kernel_launch(void* const* d_in, const int* in_sizes, int n_in,
                              void* d_out, int out_size, void* d_ws, size_t ws_size,
                              hipStream_t stream) {
    const float* emb = (const float*)d_in[0];
    const int*   ei  = (const int*)d_in[1];
    const float* W1  = (const float*)d_in[2];
    const float* b1  = (const float*)d_in[3];
    const float* Wmu = (const float*)d_in[4];
    const float* bmu = (const float*)d_in[5];
    const float* Wls = (const float*)d_in[6];
    const float* bls = (const float*)d_in[7];
    const int*   pos = (const int*)d_in[8];
    const int*   neg = (const int*)d_in[9];
    float* out = (float*)d_out;

    char* ws = (char*)d_ws;
    // small buffers
    float* dinv   = (float*)(ws);                        // 400 KB
    int*   deg    = (int*)  (ws + (512 << 10));          // 400 KB
    int*   cnt    = (int*)  (ws + (1024 << 10));         // 400 KB
    int*   rowptr = (int*)  (ws + (1536 << 10));         // 400 KB + 4
    float* accum  = (float*)(ws + (2048 << 10));         // 8 B
    // big buffers (all offsets 256B-aligned). Liveness:
    //   edges  [k_scatter8 .. k_aggH]                      12.8 MB
    //   h16    [k_h .. k_aggH]                             25.6 MB
    //   z16    [k_out .. k_loss]   ALIASES h16 (dead)      12.8 MB
    //   emb16  [k_cvt .. k_aggE]                           12.8 MB
    //   aggH16 [k_aggH .. k_out]   ALIASES emb16 (dead)    25.6 MB  <- full extent!
    //   aggE   [k_aggE .. k_h]     staged in d_out         25.6 MB
    const size_t OFF_EDGES = (2048 << 10) + 256;                 // +12.8 MB
    const size_t OFF_H16   = OFF_EDGES + (size_t)NE * 8;         // +25.6 MB
    const size_t OFF_E16   = OFF_H16 + (size_t)NN * 128 * 2;     // +25.6 MB (aggH16 extent)
    int2*  edges  = (int2*)(ws + OFF_EDGES);
    uint2* h16    = (uint2*)(ws + OFF_H16);
    uint2* z16    = (uint2*)(ws + OFF_H16);              // h16 dead by k_out
    uint4* emb16  = (uint4*)(ws + OFF_E16);
    uint4* aggH16 = (uint4*)(ws + OFF_E16);              // emb16 dead by k_aggH
    float* aggE   = out;                                 // 25.6 MB staged in d_out (dead region)

    hipMemsetAsync(deg, 0, NN * sizeof(int), stream);
    hipMemsetAsync(cnt, 0, NN * sizeof(int), stream);
    hipMemsetAsync(accum, 0, 2 * sizeof(float), stream);

    k_cvt     <<<(NN * 8 + 255) / 256, 256, 0, stream>>>((const float4*)emb, emb16);
    k_deg     <<<(NE + 255) / 256, 256, 0, stream>>>(ei, deg);
    k_dinv    <<<(NN + 255) / 256, 256, 0, stream>>>(deg, dinv);
    k_scan    <<<1, 1024, 0, stream>>>(deg, rowptr);
    k_scatter8<<<SCHUNKS * 8, 256, 0, stream>>>(ei, dinv, rowptr, cnt, edges);

    k_aggE<<<(NN * 8) / 256, 256, 0, stream>>>(emb16, dinv, rowptr, edges, (float4*)aggE);
    k_h<<<NN / 32, 256, 0, stream>>>(aggE, (const float4*)W1, b1, h16);

    k_aggH<<<(NN * 16) / 256, 256, 0, stream>>>((const uint4*)h16, dinv, rowptr, edges, aggH16);
    k_out<<<NN / 32, 256, 0, stream>>>(aggH16, (const float4*)Wmu, bmu,
                                       (const float4*)Wls, bls, out, z16);

    k_loss<<<(2 * NP * 16) / (256 * 4), 256, 0, stream>>>(pos, neg, z16, accum);
    k_fin<<<1, 1, 0, stream>>>(accum, out);
}

// Round 8
// 417.723 us; speedup vs baseline: 10.9367x; 1.0029x over previous
//
#include <hip/hip_runtime.h>
#include <hip/hip_bf16.h>
#include <hip/hip_fp16.h>

#define NN 100000      // nodes
#define NE 1600000     // edges
#define NP 100000      // pos/neg label edges
// EMB=64, HID=128, OUT=64

// ---------------- fp16 helpers ----------------
__device__ __forceinline__ void h8_to_f(const uint4 u, float* f) {
    const __half2* hp = (const __half2*)&u;
    float2 t0 = __half22float2(hp[0]), t1 = __half22float2(hp[1]);
    float2 t2 = __half22float2(hp[2]), t3 = __half22float2(hp[3]);
    f[0] = t0.x; f[1] = t0.y; f[2] = t1.x; f[3] = t1.y;
    f[4] = t2.x; f[5] = t2.y; f[6] = t3.x; f[7] = t3.y;
}

__device__ __forceinline__ void fma8(const uint4 u, float w, float* acc) {
    float f[8]; h8_to_f(u, f);
#pragma unroll
    for (int i = 0; i < 8; ++i) acc[i] = fmaf(f[i], w, acc[i]);
}

__device__ __forceinline__ uint4 f_to_h8(const float* f) {
    union { __half2 h[4]; uint4 u; } pk;
    pk.h[0] = __floats2half2_rn(f[0], f[1]);
    pk.h[1] = __floats2half2_rn(f[2], f[3]);
    pk.h[2] = __floats2half2_rn(f[4], f[5]);
    pk.h[3] = __floats2half2_rn(f[6], f[7]);
    return pk.u;
}

__device__ __forceinline__ float dot4h(uint2 a, uint2 b) {
    const __half2* ah = (const __half2*)&a;
    const __half2* bh = (const __half2*)&b;
    float2 a0 = __half22float2(ah[0]), a1 = __half22float2(ah[1]);
    float2 b0 = __half22float2(bh[0]), b1 = __half22float2(bh[1]);
    return a0.x * b0.x + a0.y * b0.y + a1.x * b1.x + a1.y * b1.y;
}

// ---------------- degree ----------------
__global__ void k_deg(const int* __restrict__ ei, int* __restrict__ deg) {
    int e = blockIdx.x * blockDim.x + threadIdx.x;
    if (e < NE) atomicAdd(&deg[ei[NE + e]], 1);
}

// ---------------- emb -> fp16 table ----------------
__global__ void k_cvt(const float4* __restrict__ in4, uint4* __restrict__ out) {
    int t = blockIdx.x * blockDim.x + threadIdx.x;   // NN*8 threads, 8 floats each
    if (t >= NN * 8) return;
    float4 a = in4[t * 2], b = in4[t * 2 + 1];
    float f[8] = {a.x, a.y, a.z, a.w, b.x, b.y, b.z, b.w};
    out[t] = f_to_h8(f);
}

// ---------------- exclusive scan over deg -> rowptr + dinv (single workgroup) --------
__global__ __launch_bounds__(1024) void k_scan(const int* __restrict__ deg,
                                               int* __restrict__ rowptr,
                                               float* __restrict__ dinv) {
    __shared__ int part[1024];
    int t = threadIdx.x;
    int lo = t * 100;                       // 1000 active threads, 100 each
    int s = 0;
    if (lo < NN) {
        const int4* d4 = (const int4*)(deg + lo);
#pragma unroll
        for (int i = 0; i < 25; ++i) { int4 d = d4[i]; s += d.x + d.y + d.z + d.w; }
    }
    part[t] = s;
    __syncthreads();
    for (int off = 1; off < 1024; off <<= 1) {
        int add = (t >= off) ? part[t - off] : 0;
        __syncthreads();
        part[t] += add;
        __syncthreads();
    }
    int run = part[t] - s;                  // exclusive prefix
    if (lo < NN) {
        const int4* d4 = (const int4*)(deg + lo);
        int4* r4 = (int4*)(rowptr + lo);
        float4* dv4 = (float4*)(dinv + lo);
#pragma unroll
        for (int i = 0; i < 25; ++i) {
            int4 d = d4[i];
            r4[i] = make_int4(run, run + d.x, run + d.x + d.y, run + d.x + d.y + d.z);
            dv4[i] = make_float4(rsqrtf((float)d.x + 1.0f), rsqrtf((float)d.y + 1.0f),
                                 rsqrtf((float)d.z + 1.0f), rsqrtf((float)d.w + 1.0f));
            run += d.x + d.y + d.z + d.w;
        }
        if (t == 999) rowptr[NN] = run;
    }
}

// ---------------- CSR build: two-pass LDS-staged counting sort ----------------
// Bucket b = dst nodes [b*RNG, (b+1)*RNG). Its CSR region is exactly
// [rowptr[b*RNG], rowptr[(b+1)*RNG]) -> per-bucket append cursors start at rowptr.
#define RNG 400
#define NBK 250       // NN / RNG
#define K_A 8000      // edges per pass-A block; 200 blocks

__global__ void k_initg(const int* __restrict__ rowptr, int* __restrict__ gcnt) {
    int i = threadIdx.x;
    if (i < NBK) gcnt[i] = rowptr[i * RNG];
}

// Pass A: chunk -> bucket-sorted in LDS -> coalesced segment append per bucket.
// Record: x = src | (dst_local << 17)  (src < 2^17, dst_local < 400 < 2^9), y = dinv[src].
__global__ __launch_bounds__(256) void k_binA(const int* __restrict__ ei,
                                              const float* __restrict__ dinv,
                                              int* __restrict__ gcnt,
                                              int2* __restrict__ edges) {
    __shared__ int2 buf[K_A];                       // 64 KB
    __shared__ int hist[NBK], lofs[NBK + 1], lcnt[NBK], gbase[NBK];
    int tid = threadIdx.x;
    int e0 = blockIdx.x * K_A;
    for (int i = tid; i < NBK; i += 256) { hist[i] = 0; lcnt[i] = 0; }
    __syncthreads();
    // count
    for (int i = tid; i < K_A; i += 256) {
        int d = ei[NE + e0 + i];
        atomicAdd(&hist[d / RNG], 1);
    }
    __syncthreads();
    // exclusive scan (wave 0) + global segment claim (all threads)
    if (tid < 64) {
        int run = 0;
        for (int g = 0; g < NBK; g += 64) {
            int idx = g + tid;
            int v = (idx < NBK) ? hist[idx] : 0;
            int inc = v;
#pragma unroll
            for (int off = 1; off < 64; off <<= 1) {
                int tt = __shfl_up(inc, off);
                if (tid >= off) inc += tt;
            }
            if (idx < NBK) lofs[idx] = run + inc - v;
            run += __shfl(inc, 63);
        }
        if (tid == 0) lofs[NBK] = run;              // == K_A
    }
    for (int i = tid; i < NBK; i += 256) gbase[i] = atomicAdd(&gcnt[i], hist[i]);
    __syncthreads();
    // place into LDS, bucket-sorted (chunk re-read is L2-hot)
    for (int i = tid; i < K_A; i += 256) {
        int s = ei[e0 + i], d = ei[NE + e0 + i];
        int b = d / RNG;
        int dl = d - b * RNG;
        int p = lofs[b] + atomicAdd(&lcnt[b], 1);
        buf[p] = make_int2(s | (dl << 17), __float_as_int(dinv[s]));
    }
    __syncthreads();
    // coalesced dump: flat index -> bucket via binary search on lofs
    for (int j = tid; j < K_A; j += 256) {
        int loB = 0, hiB = NBK;
        while (hiB - loB > 1) {
            int mid = (loB + hiB) >> 1;
            if (lofs[mid] <= j) loB = mid; else hiB = mid;
        }
        edges[gbase[loB] + (j - lofs[loB])] = buf[j];
    }
}

// Pass B: per bucket, reorder region into exact per-dst CSR slots via LDS staging.
// In-place safe: all reads complete before the sync; writes are fully coalesced.
#define CAPB 8192     // mean region 6400, sigma ~80 -> +22 sigma; reg-overflow beyond
__global__ __launch_bounds__(256) void k_binB(const int* __restrict__ rowptr,
                                              int2* __restrict__ edges) {
    __shared__ int2 buf[CAPB];                      // 64 KB
    __shared__ int lrp[RNG + 1];
    __shared__ int lcnt2[RNG];
    int tid = threadIdx.x;
    int lo = blockIdx.x * RNG;
    for (int i = tid; i <= RNG; i += 256) lrp[i] = rowptr[lo + i];
    for (int i = tid; i < RNG; i += 256) lcnt2[i] = 0;
    __syncthreads();
    int base = lrp[0], n = lrp[RNG] - base;
    int ovS0 = -1, ovS1 = -1;
    int2 ovR0 = make_int2(0, 0), ovR1 = make_int2(0, 0);
    for (int i = tid; i < n; i += 256) {
        int2 rec = edges[base + i];
        int dl = ((unsigned)rec.x) >> 17;
        int src = rec.x & 0x1FFFF;
        int slot = (lrp[dl] - base) + atomicAdd(&lcnt2[dl], 1);
        int2 orec = make_int2(src, rec.y);
        if (slot < CAPB) buf[slot] = orec;
        else if (ovS0 < 0) { ovS0 = slot; ovR0 = orec; }
        else { ovS1 = slot; ovR1 = orec; }
    }
    __syncthreads();
    int lim = n < CAPB ? n : CAPB;
    for (int i = tid; i < lim; i += 256) edges[base + i] = buf[i];
    if (ovS0 >= 0) edges[base + ovS0] = ovR0;
    if (ovS1 >= 0) edges[base + ovS1] = ovR1;
}

// ---------------- gather-aggregate, 64 feats fp16 in / fp32 out: 8 lanes per row ----------------
__global__ __launch_bounds__(256) void k_aggE(const uint4* __restrict__ x16,
                                              const float* __restrict__ dinv,
                                              const int* __restrict__ rowptr,
                                              const int2* __restrict__ edges,
                                              float4* __restrict__ agg4) {
    int t = blockIdx.x * blockDim.x + threadIdx.x;   // grid = NN*8 exactly
    int r = t >> 3, q = t & 7;
    float dr = dinv[r];
    float acc[8];
    {
        float f[8]; h8_to_f(x16[(size_t)r * 8 + q], f);
        float sc = dr * dr;
#pragma unroll
        for (int i = 0; i < 8; ++i) acc[i] = f[i] * sc;
    }
    int j = rowptr[r], j1 = rowptr[r + 1];
    for (; j + 8 <= j1; j += 8) {
        int2 e[8]; uint4 v[8];
#pragma unroll
        for (int i = 0; i < 8; ++i) e[i] = edges[j + i];
#pragma unroll
        for (int i = 0; i < 8; ++i) v[i] = x16[(size_t)e[i].x * 8 + q];
#pragma unroll
        for (int i = 0; i < 8; ++i) fma8(v[i], __int_as_float(e[i].y) * dr, acc);
    }
    if (j + 4 <= j1) {
        int2 e[4]; uint4 v[4];
#pragma unroll
        for (int i = 0; i < 4; ++i) e[i] = edges[j + i];
#pragma unroll
        for (int i = 0; i < 4; ++i) v[i] = x16[(size_t)e[i].x * 8 + q];
#pragma unroll
        for (int i = 0; i < 4; ++i) fma8(v[i], __int_as_float(e[i].y) * dr, acc);
        j += 4;
    }
    for (; j < j1; ++j) {
        int2 e = edges[j];
        fma8(x16[(size_t)e.x * 8 + q], __int_as_float(e.y) * dr, acc);
    }
    size_t o = (size_t)r * 16 + q * 2;
    agg4[o]     = make_float4(acc[0], acc[1], acc[2], acc[3]);
    agg4[o + 1] = make_float4(acc[4], acc[5], acc[6], acc[7]);
}

// ---------------- gather-aggregate, 128 feats fp16 in / fp16 out: 16 lanes per row ----------------
__global__ __launch_bounds__(256) void k_aggH(const uint4* __restrict__ x16,
                                              const float* __restrict__ dinv,
                                              const int* __restrict__ rowptr,
                                              const int2* __restrict__ edges,
                                              uint4* __restrict__ aggH16) {
    int t = blockIdx.x * blockDim.x + threadIdx.x;   // grid = NN*16 exactly
    int r = t >> 4, q = t & 15;
    float dr = dinv[r];
    float acc[8];
    {
        float f[8]; h8_to_f(x16[(size_t)r * 16 + q], f);
        float sc = dr * dr;
#pragma unroll
        for (int i = 0; i < 8; ++i) acc[i] = f[i] * sc;
    }
    int j = rowptr[r], j1 = rowptr[r + 1];
    for (; j + 8 <= j1; j += 8) {
        int2 e[8]; uint4 v[8];
#pragma unroll
        for (int i = 0; i < 8; ++i) e[i] = edges[j + i];
#pragma unroll
        for (int i = 0; i < 8; ++i) v[i] = x16[(size_t)e[i].x * 16 + q];
#pragma unroll
        for (int i = 0; i < 8; ++i) fma8(v[i], __int_as_float(e[i].y) * dr, acc);
    }
    if (j + 4 <= j1) {
        int2 e[4]; uint4 v[4];
#pragma unroll
        for (int i = 0; i < 4; ++i) e[i] = edges[j + i];
#pragma unroll
        for (int i = 0; i < 4; ++i) v[i] = x16[(size_t)e[i].x * 16 + q];
#pragma unroll
        for (int i = 0; i < 4; ++i) fma8(v[i], __int_as_float(e[i].y) * dr, acc);
        j += 4;
    }
    for (; j < j1; ++j) {
        int2 e = edges[j];
        fma8(x16[(size_t)e.x * 16 + q], __int_as_float(e.y) * dr, acc);
    }
    aggH16[(size_t)r * 16 + q] = f_to_h8(acc);
}

// ---------------- h = relu(aggE @ W1 + b1), [N,64]x[64,128], 4x4 register tile ----------------
__global__ __launch_bounds__(256) void k_h(const float* __restrict__ aggE,
                                           const float4* __restrict__ W1_4,  // [64][32] f4
                                           const float* __restrict__ b1,
                                           uint2* __restrict__ h16) {
    __shared__ float4 w4[64 * 32];     // w4[k*32+jg] = W1[k][4jg..4jg+3]
    __shared__ float rows[32 * 65];    // padded
    int t = threadIdx.x;
    int base = blockIdx.x * 32;
#pragma unroll
    for (int i = 0; i < 8; ++i) w4[t + i * 256] = W1_4[t + i * 256];
#pragma unroll
    for (int i = 0; i < 8; ++i) {
        int idx = t + i * 256;
        int r = idx >> 6, kk = idx & 63;
        rows[r * 65 + kk] = aggE[(size_t)(base + r) * 64 + kk];
    }
    __syncthreads();
    int rg = t >> 5, jg = t & 31;
    int r0 = rg * 4;
    float4 bias = ((const float4*)b1)[jg];
    float acc[4][4];
#pragma unroll
    for (int r = 0; r < 4; ++r) {
        acc[r][0] = bias.x; acc[r][1] = bias.y; acc[r][2] = bias.z; acc[r][3] = bias.w;
    }
#pragma unroll 8
    for (int k = 0; k < 64; ++k) {
        float4 w = w4[k * 32 + jg];
        float rv0 = rows[(r0 + 0) * 65 + k];
        float rv1 = rows[(r0 + 1) * 65 + k];
        float rv2 = rows[(r0 + 2) * 65 + k];
        float rv3 = rows[(r0 + 3) * 65 + k];
        acc[0][0] = fmaf(rv0, w.x, acc[0][0]); acc[0][1] = fmaf(rv0, w.y, acc[0][1]);
        acc[0][2] = fmaf(rv0, w.z, acc[0][2]); acc[0][3] = fmaf(rv0, w.w, acc[0][3]);
        acc[1][0] = fmaf(rv1, w.x, acc[1][0]); acc[1][1] = fmaf(rv1, w.y, acc[1][1]);
        acc[1][2] = fmaf(rv1, w.z, acc[1][2]); acc[1][3] = fmaf(rv1, w.w, acc[1][3]);
        acc[2][0] = fmaf(rv2, w.x, acc[2][0]); acc[2][1] = fmaf(rv2, w.y, acc[2][1]);
        acc[2][2] = fmaf(rv2, w.z, acc[2][2]); acc[2][3] = fmaf(rv2, w.w, acc[2][3]);
        acc[3][0] = fmaf(rv3, w.x, acc[3][0]); acc[3][1] = fmaf(rv3, w.y, acc[3][1]);
        acc[3][2] = fmaf(rv3, w.z, acc[3][2]); acc[3][3] = fmaf(rv3, w.w, acc[3][3]);
    }
#pragma unroll
    for (int r = 0; r < 4; ++r) {
        union { __half2 h[2]; uint2 u; } pk;
        pk.h[0] = __floats2half2_rn(fmaxf(acc[r][0], 0.0f), fmaxf(acc[r][1], 0.0f));
        pk.h[1] = __floats2half2_rn(fmaxf(acc[r][2], 0.0f), fmaxf(acc[r][3], 0.0f));
        h16[(size_t)(base + r0 + r) * 32 + jg] = pk.u;
    }
}

// ---------------- mu/logstd = aggH @ [Wmu|Wls] + b, fp16 aggH in, 4x4 tile ----------------
// Also emits fp16 copy of z (=mu) for the decoder.
__global__ __launch_bounds__(256) void k_out(const uint4* __restrict__ aggH16,
                                             const float4* __restrict__ Wmu4, // [128][16] f4
                                             const float* __restrict__ bmu,
                                             const float4* __restrict__ Wls4, // [128][16] f4
                                             const float* __restrict__ bls,
                                             float* __restrict__ out,
                                             uint2* __restrict__ z16) {
    __shared__ float4 w4[64 * 32];     // w4[kk*32+jj] = W[kh*64+kk][4jj..4jj+3] combined
    __shared__ float rows[32 * 129];   // padded, full 128 feats
    int t = threadIdx.x;
    int base = blockIdx.x * 32;
#pragma unroll
    for (int i = 0; i < 2; ++i) {
        int idx = t + i * 256;          // 512 uint4 total = 32 rows x 16
        int r = idx >> 4, c = idx & 15;
        float f[8]; h8_to_f(aggH16[(size_t)(base + r) * 16 + c], f);
#pragma unroll
        for (int kk = 0; kk < 8; ++kk) rows[r * 129 + c * 8 + kk] = f[kk];
    }
    int rg = t >> 5, jg = t & 31;
    int r0 = rg * 4;
    float4 bias = (jg < 16) ? ((const float4*)bmu)[jg] : ((const float4*)bls)[jg - 16];
    float acc[4][4];
#pragma unroll
    for (int r = 0; r < 4; ++r) {
        acc[r][0] = bias.x; acc[r][1] = bias.y; acc[r][2] = bias.z; acc[r][3] = bias.w;
    }
    for (int kh = 0; kh < 2; ++kh) {
        if (kh) __syncthreads();      // all waves done reading previous w4
#pragma unroll
        for (int i = 0; i < 8; ++i) {
            int idx = t + i * 256;
            int jj = idx & 31, kk = idx >> 5;
            int k = kh * 64 + kk;
            w4[idx] = (jj < 16) ? Wmu4[k * 16 + jj] : Wls4[k * 16 + (jj - 16)];
        }
        __syncthreads();
#pragma unroll 8
        for (int kk = 0; kk < 64; ++kk) {
            int k = kh * 64 + kk;
            float4 w = w4[kk * 32 + jg];
            float rv0 = rows[(r0 + 0) * 129 + k];
            float rv1 = rows[(r0 + 1) * 129 + k];
            float rv2 = rows[(r0 + 2) * 129 + k];
            float rv3 = rows[(r0 + 3) * 129 + k];
            acc[0][0] = fmaf(rv0, w.x, acc[0][0]); acc[0][1] = fmaf(rv0, w.y, acc[0][1]);
            acc[0][2] = fmaf(rv0, w.z, acc[0][2]); acc[0][3] = fmaf(rv0, w.w, acc[0][3]);
            acc[1][0] = fmaf(rv1, w.x, acc[1][0]); acc[1][1] = fmaf(rv1, w.y, acc[1][1]);
            acc[1][2] = fmaf(rv1, w.z, acc[1][2]); acc[1][3] = fmaf(rv1, w.w, acc[1][3]);
            acc[2][0] = fmaf(rv2, w.x, acc[2][0]); acc[2][1] = fmaf(rv2, w.y, acc[2][1]);
            acc[2][2] = fmaf(rv2, w.z, acc[2][2]); acc[2][3] = fmaf(rv2, w.w, acc[2][3]);
            acc[3][0] = fmaf(rv3, w.x, acc[3][0]); acc[3][1] = fmaf(rv3, w.y, acc[3][1]);
            acc[3][2] = fmaf(rv3, w.z, acc[3][2]); acc[3][3] = fmaf(rv3, w.w, acc[3][3]);
        }
    }
    float4* out4 = (float4*)out;
    if (jg < 16) {
#pragma unroll
        for (int r = 0; r < 4; ++r) {
            out4[(size_t)(base + r0 + r) * 16 + jg] =
                make_float4(acc[r][0], acc[r][1], acc[r][2], acc[r][3]);
            union { __half2 h[2]; uint2 u; } pk;
            pk.h[0] = __floats2half2_rn(acc[r][0], acc[r][1]);
            pk.h[1] = __floats2half2_rn(acc[r][2], acc[r][3]);
            z16[(size_t)(base + r0 + r) * 16 + jg] = pk.u;
        }
    } else {
#pragma unroll
        for (int r = 0; r < 4; ++r) {
            float4 o = make_float4(fminf(acc[r][0], 10.0f), fminf(acc[r][1], 10.0f),
                                   fminf(acc[r][2], 10.0f), fminf(acc[r][3], 10.0f));
            out4[(size_t)NN * 16 + (size_t)(base + r0 + r) * 16 + (jg - 16)] = o;
        }
    }
}

// ---------------- decoder loss: fp16 z, 4 edges per 16-lane group ----------------
__global__ __launch_bounds__(256) void k_loss(const int* __restrict__ pos,
                                              const int* __restrict__ neg,
                                              const uint2* __restrict__ z16,
                                              float* __restrict__ accum) {
    int t = blockIdx.x * blockDim.x + threadIdx.x;
    int grp = t >> 4, q = t & 15;
    int e0 = grp * 4;                          // 4 consecutive ids in [0, 2*NP)
    bool isNeg = e0 >= NP;                     // uniform within group (NP % 4 == 0)
    const int* idx = isNeg ? neg : pos;
    int eb = isNeg ? e0 - NP : e0;
    int a0 = idx[eb + 0], b0 = idx[NP + eb + 0];
    int a1 = idx[eb + 1], b1 = idx[NP + eb + 1];
    int a2 = idx[eb + 2], b2 = idx[NP + eb + 2];
    int a3 = idx[eb + 3], b3 = idx[NP + eb + 3];
    uint2 ua0 = z16[(size_t)a0 * 16 + q], ub0 = z16[(size_t)b0 * 16 + q];
    uint2 ua1 = z16[(size_t)a1 * 16 + q], ub1 = z16[(size_t)b1 * 16 + q];
    uint2 ua2 = z16[(size_t)a2 * 16 + q], ub2 = z16[(size_t)b2 * 16 + q];
    uint2 ua3 = z16[(size_t)a3 * 16 + q], ub3 = z16[(size_t)b3 * 16 + q];
    float d0 = dot4h(ua0, ub0);
    float d1 = dot4h(ua1, ub1);
    float d2 = dot4h(ua2, ub2);
    float d3 = dot4h(ua3, ub3);
#pragma unroll
    for (int off = 1; off < 16; off <<= 1) {
        d0 += __shfl_xor(d0, off);
        d1 += __shfl_xor(d1, off);
        d2 += __shfl_xor(d2, off);
        d3 += __shfl_xor(d3, off);
    }
    __shared__ float bsum[2];
    if (threadIdx.x < 2) bsum[threadIdx.x] = 0.0f;
    __syncthreads();
    if (q == 0) {
        float term;
        if (isNeg) {
            term = logf(1.0f - 1.0f / (1.0f + expf(-d0)) + 1e-15f)
                 + logf(1.0f - 1.0f / (1.0f + expf(-d1)) + 1e-15f)
                 + logf(1.0f - 1.0f / (1.0f + expf(-d2)) + 1e-15f)
                 + logf(1.0f - 1.0f / (1.0f + expf(-d3)) + 1e-15f);
        } else {
            term = logf(1.0f / (1.0f + expf(-d0)) + 1e-15f)
                 + logf(1.0f / (1.0f + expf(-d1)) + 1e-15f)
                 + logf(1.0f / (1.0f + expf(-d2)) + 1e-15f)
                 + logf(1.0f / (1.0f + expf(-d3)) + 1e-15f);
        }
        atomicAdd(&bsum[isNeg ? 1 : 0], term);
    }
    __syncthreads();
    if (threadIdx.x < 2) atomicAdd(&accum[threadIdx.x], bsum[threadIdx.x]);
}

__global__ void k_fin(const float* __restrict__ accum, float* __restrict__ out) {
    out[(size_t)NN * 128] = -(accum[0] + accum[1]) * (1.0f / (float)NP);
}

extern "C" void kernel_launch(void* const* d_in, const int* in_sizes, int n_in,
                              void* d_out, int out_size, void* d_ws, size_t ws_size,
                              hipStream_t stream) {
    const float* emb = (const float*)d_in[0];
    const int*   ei  = (const int*)d_in[1];
    const float* W1  = (const float*)d_in[2];
    const float* b1  = (const float*)d_in[3];
    const float* Wmu = (const float*)d_in[4];
    const float* bmu = (const float*)d_in[5];
    const float* Wls = (const float*)d_in[6];
    const float* bls = (const float*)d_in[7];
    const int*   pos = (const int*)d_in[8];
    const int*   neg = (const int*)d_in[9];
    float* out = (float*)d_out;

    char* ws = (char*)d_ws;
    // small buffers
    float* dinv   = (float*)(ws);                        // 400 KB
    int*   deg    = (int*)  (ws + (512 << 10));          // 400 KB
    int*   gcnt   = (int*)  (ws + (1024 << 10));         // 1 KB (bucket cursors)
    int*   rowptr = (int*)  (ws + (1536 << 10));         // 400 KB + 4
    float* accum  = (float*)(ws + (2048 << 10));         // 8 B
    // big buffers (all offsets 256B-aligned). Liveness:
    //   edges  [k_binA .. k_aggH]                          12.8 MB
    //   h16    [k_h .. k_aggH]                             25.6 MB
    //   z16    [k_out .. k_loss]   ALIASES h16 (dead)      12.8 MB
    //   emb16  [k_cvt .. k_aggE]                           12.8 MB
    //   aggH16 [k_aggH .. k_out]   ALIASES emb16 (dead)    25.6 MB  <- full extent!
    //   aggE   [k_aggE .. k_h]     staged in d_out         25.6 MB
    const size_t OFF_EDGES = (2048 << 10) + 256;                 // +12.8 MB
    const size_t OFF_H16   = OFF_EDGES + (size_t)NE * 8;         // +25.6 MB
    const size_t OFF_E16   = OFF_H16 + (size_t)NN * 128 * 2;     // +25.6 MB (aggH16 extent)
    int2*  edges  = (int2*)(ws + OFF_EDGES);
    uint2* h16    = (uint2*)(ws + OFF_H16);
    uint2* z16    = (uint2*)(ws + OFF_H16);              // h16 dead by k_out
    uint4* emb16  = (uint4*)(ws + OFF_E16);
    uint4* aggH16 = (uint4*)(ws + OFF_E16);              // emb16 dead by k_aggH
    float* aggE   = out;                                 // 25.6 MB staged in d_out (dead region)

    hipMemsetAsync(deg, 0, NN * sizeof(int), stream);
    hipMemsetAsync(accum, 0, 2 * sizeof(float), stream);

    k_cvt  <<<(NN * 8 + 255) / 256, 256, 0, stream>>>((const float4*)emb, emb16);
    k_deg  <<<(NE + 255) / 256, 256, 0, stream>>>(ei, deg);
    k_scan <<<1, 1024, 0, stream>>>(deg, rowptr, dinv);
    k_initg<<<1, 256, 0, stream>>>(rowptr, gcnt);
    k_binA <<<NE / K_A, 256, 0, stream>>>(ei, dinv, gcnt, edges);
    k_binB <<<NBK, 256, 0, stream>>>(rowptr, edges);

    k_aggE<<<(NN * 8) / 256, 256, 0, stream>>>(emb16, dinv, rowptr, edges, (float4*)aggE);
    k_h<<<NN / 32, 256, 0, stream>>>(aggE, (const float4*)W1, b1, h16);

    k_aggH<<<(NN * 16) / 256, 256, 0, stream>>>((const uint4*)h16, dinv, rowptr, edges, aggH16);
    k_out<<<NN / 32, 256, 0, stream>>>(aggH16, (const float4*)Wmu, bmu,
                                       (const float4*)Wls, bls, out, z16);

    k_loss<<<(2 * NP * 16) / (256 * 4), 256, 0, stream>>>(pos, neg, z16, accum);
    k_fin<<<1, 1, 0, stream>>>(accum, out);
}

// Round 9
// 307.351 us; speedup vs baseline: 14.8642x; 1.3591x over previous
//
#include <hip/hip_runtime.h>
#include <hip/hip_bf16.h>
#include <hip/hip_fp16.h>

#define NN 100000      // nodes
#define NE 1600000     // edges
#define NP 100000      // pos/neg label edges
// EMB=64, HID=128, OUT=64

// ---------------- fp16 helpers ----------------
__device__ __forceinline__ void h8_to_f(const uint4 u, float* f) {
    const __half2* hp = (const __half2*)&u;
    float2 t0 = __half22float2(hp[0]), t1 = __half22float2(hp[1]);
    float2 t2 = __half22float2(hp[2]), t3 = __half22float2(hp[3]);
    f[0] = t0.x; f[1] = t0.y; f[2] = t1.x; f[3] = t1.y;
    f[4] = t2.x; f[5] = t2.y; f[6] = t3.x; f[7] = t3.y;
}

__device__ __forceinline__ void add8(const uint4 u, float* acc) {
    float f[8]; h8_to_f(u, f);
#pragma unroll
    for (int i = 0; i < 8; ++i) acc[i] += f[i];
}

__device__ __forceinline__ uint4 f_to_h8(const float* f) {
    union { __half2 h[4]; uint4 u; } pk;
    pk.h[0] = __floats2half2_rn(f[0], f[1]);
    pk.h[1] = __floats2half2_rn(f[2], f[3]);
    pk.h[2] = __floats2half2_rn(f[4], f[5]);
    pk.h[3] = __floats2half2_rn(f[6], f[7]);
    return pk.u;
}

__device__ __forceinline__ float dot4h(uint2 a, uint2 b) {
    const __half2* ah = (const __half2*)&a;
    const __half2* bh = (const __half2*)&b;
    float2 a0 = __half22float2(ah[0]), a1 = __half22float2(ah[1]);
    float2 b0 = __half22float2(bh[0]), b1 = __half22float2(bh[1]);
    return a0.x * b0.x + a0.y * b0.y + a1.x * b1.x + a1.y * b1.y;
}

// ---------------- CSR build: bucket histogram -> scan -> 2-pass counting sort --------
#define RNG 400
#define NBK 250       // NN / RNG
#define K_A 8000      // edges per pass-A block; 200 blocks
#define CAPB 12288    // pass-B LDS staging (mean region 6400)

// per-chunk LDS histogram of dst buckets
__global__ __launch_bounds__(256) void k_hist(const int* __restrict__ ei,
                                              int* __restrict__ bcnt) {
    __shared__ int hist[NBK];
    int tid = threadIdx.x;
    int e0 = blockIdx.x * K_A;
    for (int i = tid; i < NBK; i += 256) hist[i] = 0;
    __syncthreads();
    for (int i = tid; i < K_A; i += 256) atomicAdd(&hist[ei[NE + e0 + i] / RNG], 1);
    __syncthreads();
    for (int i = tid; i < NBK; i += 256) if (hist[i]) atomicAdd(&bcnt[i], hist[i]);
}

// scan 250 bucket counts -> bbase[251]; init append cursors
__global__ __launch_bounds__(256) void k_bscan(const int* __restrict__ bcnt,
                                               int* __restrict__ bbase,
                                               int* __restrict__ gcnt) {
    __shared__ int c[NBK];
    int tid = threadIdx.x;
    if (tid < NBK) c[tid] = bcnt[tid];
    __syncthreads();
    if (tid < 64) {
        int run = 0;
        for (int g = 0; g < NBK; g += 64) {
            int idx = g + tid;
            int v = (idx < NBK) ? c[idx] : 0;
            int inc = v;
#pragma unroll
            for (int off = 1; off < 64; off <<= 1) {
                int t2 = __shfl_up(inc, off);
                if (tid >= off) inc += t2;
            }
            if (idx < NBK) { int ex = run + inc - v; bbase[idx] = ex; gcnt[idx] = ex; }
            run += __shfl(inc, 63);
        }
        if (tid == 0) bbase[NBK] = run;
    }
}

// Pass A: chunk -> bucket-sorted in LDS -> coalesced segment append per bucket.
// Record (4B): src | (dst_local << 17)   (src < 2^17, dst_local < 400 < 2^9)
__global__ __launch_bounds__(256) void k_binA(const int* __restrict__ ei,
                                              int* __restrict__ gcnt,
                                              int* __restrict__ edges) {
    __shared__ int buf[K_A];                        // 32 KB
    __shared__ int hist[NBK], lofs[NBK + 1], lcnt[NBK], gbase[NBK];
    int tid = threadIdx.x;
    int e0 = blockIdx.x * K_A;
    for (int i = tid; i < NBK; i += 256) { hist[i] = 0; lcnt[i] = 0; }
    __syncthreads();
    for (int i = tid; i < K_A; i += 256) atomicAdd(&hist[ei[NE + e0 + i] / RNG], 1);
    __syncthreads();
    if (tid < 64) {
        int run = 0;
        for (int g = 0; g < NBK; g += 64) {
            int idx = g + tid;
            int v = (idx < NBK) ? hist[idx] : 0;
            int inc = v;
#pragma unroll
            for (int off = 1; off < 64; off <<= 1) {
                int t2 = __shfl_up(inc, off);
                if (tid >= off) inc += t2;
            }
            if (idx < NBK) lofs[idx] = run + inc - v;
            run += __shfl(inc, 63);
        }
        if (tid == 0) lofs[NBK] = run;              // == K_A
    }
    for (int i = tid; i < NBK; i += 256) gbase[i] = atomicAdd(&gcnt[i], hist[i]);
    __syncthreads();
    for (int i = tid; i < K_A; i += 256) {
        int s = ei[e0 + i], d = ei[NE + e0 + i];
        int b = d / RNG;
        int dl = d - b * RNG;
        int p = lofs[b] + atomicAdd(&lcnt[b], 1);
        buf[p] = s | (dl << 17);
    }
    __syncthreads();
    for (int j = tid; j < K_A; j += 256) {
        int loB = 0, hiB = NBK;
        while (hiB - loB > 1) {
            int mid = (loB + hiB) >> 1;
            if (lofs[mid] <= j) loB = mid; else hiB = mid;
        }
        edges[gbase[loB] + (j - lofs[loB])] = buf[j];
    }
}

// Pass B: per bucket -- local per-dst histogram -> deg/dinv + rowptr (coalesced),
// then in-place reorder of the region into exact per-dst CSR slots via LDS.
__global__ __launch_bounds__(256) void k_binB(const int* __restrict__ bbase,
                                              int* __restrict__ edges,
                                              int* __restrict__ rowptr,
                                              float* __restrict__ dinv) {
    __shared__ int buf[CAPB];                       // 48 KB
    __shared__ int hist[RNG], lrp[RNG], lcnt[RNG];
    int tid = threadIdx.x;
    int b = blockIdx.x;
    int lo = b * RNG;
    int base = bbase[b], n = bbase[b + 1] - base;
    for (int i = tid; i < RNG; i += 256) { hist[i] = 0; lcnt[i] = 0; }
    __syncthreads();
    for (int i = tid; i < n; i += 256)
        atomicAdd(&hist[((unsigned)edges[base + i]) >> 17], 1);
    __syncthreads();
    if (tid < 64) {
        int run = 0;
        for (int g = 0; g < RNG; g += 64) {
            int idx = g + tid;
            int v = (idx < RNG) ? hist[idx] : 0;
            int inc = v;
#pragma unroll
            for (int off = 1; off < 64; off <<= 1) {
                int t2 = __shfl_up(inc, off);
                if (tid >= off) inc += t2;
            }
            if (idx < RNG) lrp[idx] = run + inc - v;
            run += __shfl(inc, 63);
        }
    }
    __syncthreads();
    for (int i = tid; i < RNG; i += 256) {
        dinv[lo + i] = rsqrtf((float)hist[i] + 1.0f);
        rowptr[lo + i] = base + lrp[i];
    }
    if (b == NBK - 1 && tid == 0) rowptr[NN] = base + n;
    int ovS0 = -1, ovS1 = -1, ovR0 = 0, ovR1 = 0;
    for (int i = tid; i < n; i += 256) {
        int rec = edges[base + i];
        int dl = ((unsigned)rec) >> 17;
        int src = rec & 0x1FFFF;
        int slot = lrp[dl] + atomicAdd(&lcnt[dl], 1);
        if (slot < CAPB) buf[slot] = src;
        else if (ovS0 < 0) { ovS0 = slot; ovR0 = src; }
        else { ovS1 = slot; ovR1 = src; }
    }
    __syncthreads();
    int lim = n < CAPB ? n : CAPB;
    for (int i = tid; i < lim; i += 256) edges[base + i] = buf[i];
    if (ovS0 >= 0) edges[base + ovS0] = ovR0;
    if (ovS1 >= 0) edges[base + ovS1] = ovR1;
}

// ---------------- emb -> fp16 table, pre-scaled by dinv ----------------
__global__ void k_cvt(const float4* __restrict__ in4, const float* __restrict__ dinv,
                      uint4* __restrict__ out) {
    int t = blockIdx.x * blockDim.x + threadIdx.x;   // NN*8 threads, 8 floats each
    if (t >= NN * 8) return;
    float dv = dinv[t >> 3];
    float4 a = in4[t * 2], b = in4[t * 2 + 1];
    float f[8] = {a.x * dv, a.y * dv, a.z * dv, a.w * dv,
                  b.x * dv, b.y * dv, b.z * dv, b.w * dv};
    out[t] = f_to_h8(f);
}

// ---------------- gather-aggregate, 64 feats: pure sum of pre-scaled rows ------------
// agg[r] = dinv[r] * (x'[r] + sum_{s in N(r)} x'[s]),  x' = x * dinv
__global__ __launch_bounds__(256) void k_aggE(const uint4* __restrict__ x16,
                                              const float* __restrict__ dinv,
                                              const int* __restrict__ rowptr,
                                              const int* __restrict__ edges,
                                              float4* __restrict__ agg4) {
    int t = blockIdx.x * blockDim.x + threadIdx.x;   // grid = NN*8 exactly
    int r = t >> 3, q = t & 7;
    float dr = dinv[r];
    float acc[8];
    h8_to_f(x16[(size_t)r * 8 + q], acc);            // self term x'[r]
    int j = rowptr[r], j1 = rowptr[r + 1];
    for (; j + 8 <= j1; j += 8) {
        int e[8]; uint4 v[8];
#pragma unroll
        for (int i = 0; i < 8; ++i) e[i] = edges[j + i];
#pragma unroll
        for (int i = 0; i < 8; ++i) v[i] = x16[(size_t)e[i] * 8 + q];
#pragma unroll
        for (int i = 0; i < 8; ++i) add8(v[i], acc);
    }
    if (j + 4 <= j1) {
        int e[4]; uint4 v[4];
#pragma unroll
        for (int i = 0; i < 4; ++i) e[i] = edges[j + i];
#pragma unroll
        for (int i = 0; i < 4; ++i) v[i] = x16[(size_t)e[i] * 8 + q];
#pragma unroll
        for (int i = 0; i < 4; ++i) add8(v[i], acc);
        j += 4;
    }
    for (; j < j1; ++j) add8(x16[(size_t)edges[j] * 8 + q], acc);
    size_t o = (size_t)r * 16 + q * 2;
    agg4[o]     = make_float4(acc[0] * dr, acc[1] * dr, acc[2] * dr, acc[3] * dr);
    agg4[o + 1] = make_float4(acc[4] * dr, acc[5] * dr, acc[6] * dr, acc[7] * dr);
}

// ---------------- gather-aggregate, 128 feats: pure sum, fp16 out ----------------
__global__ __launch_bounds__(256) void k_aggH(const uint4* __restrict__ x16,
                                              const float* __restrict__ dinv,
                                              const int* __restrict__ rowptr,
                                              const int* __restrict__ edges,
                                              uint4* __restrict__ aggH16) {
    int t = blockIdx.x * blockDim.x + threadIdx.x;   // grid = NN*16 exactly
    int r = t >> 4, q = t & 15;
    float dr = dinv[r];
    float acc[8];
    h8_to_f(x16[(size_t)r * 16 + q], acc);           // self term h'[r]
    int j = rowptr[r], j1 = rowptr[r + 1];
    for (; j + 8 <= j1; j += 8) {
        int e[8]; uint4 v[8];
#pragma unroll
        for (int i = 0; i < 8; ++i) e[i] = edges[j + i];
#pragma unroll
        for (int i = 0; i < 8; ++i) v[i] = x16[(size_t)e[i] * 16 + q];
#pragma unroll
        for (int i = 0; i < 8; ++i) add8(v[i], acc);
    }
    if (j + 4 <= j1) {
        int e[4]; uint4 v[4];
#pragma unroll
        for (int i = 0; i < 4; ++i) e[i] = edges[j + i];
#pragma unroll
        for (int i = 0; i < 4; ++i) v[i] = x16[(size_t)e[i] * 16 + q];
#pragma unroll
        for (int i = 0; i < 4; ++i) add8(v[i], acc);
        j += 4;
    }
    for (; j < j1; ++j) add8(x16[(size_t)edges[j] * 16 + q], acc);
    float o[8];
#pragma unroll
    for (int i = 0; i < 8; ++i) o[i] = acc[i] * dr;
    aggH16[(size_t)r * 16 + q] = f_to_h8(o);
}

// ---------------- h' = relu(aggE @ W1 + b1) * dinv, 4x4 register tile ----------------
__global__ __launch_bounds__(256) void k_h(const float* __restrict__ aggE,
                                           const float4* __restrict__ W1_4,  // [64][32] f4
                                           const float* __restrict__ b1,
                                           const float* __restrict__ dinv,
                                           uint2* __restrict__ h16) {
    __shared__ float4 w4[64 * 32];     // w4[k*32+jg] = W1[k][4jg..4jg+3]
    __shared__ float rows[32 * 65];    // padded
    __shared__ float sdinv[32];
    int t = threadIdx.x;
    int base = blockIdx.x * 32;
#pragma unroll
    for (int i = 0; i < 8; ++i) w4[t + i * 256] = W1_4[t + i * 256];
#pragma unroll
    for (int i = 0; i < 8; ++i) {
        int idx = t + i * 256;
        int r = idx >> 6, kk = idx & 63;
        rows[r * 65 + kk] = aggE[(size_t)(base + r) * 64 + kk];
    }
    if (t < 32) sdinv[t] = dinv[base + t];
    __syncthreads();
    int rg = t >> 5, jg = t & 31;
    int r0 = rg * 4;
    float4 bias = ((const float4*)b1)[jg];
    float acc[4][4];
#pragma unroll
    for (int r = 0; r < 4; ++r) {
        acc[r][0] = bias.x; acc[r][1] = bias.y; acc[r][2] = bias.z; acc[r][3] = bias.w;
    }
#pragma unroll 8
    for (int k = 0; k < 64; ++k) {
        float4 w = w4[k * 32 + jg];
        float rv0 = rows[(r0 + 0) * 65 + k];
        float rv1 = rows[(r0 + 1) * 65 + k];
        float rv2 = rows[(r0 + 2) * 65 + k];
        float rv3 = rows[(r0 + 3) * 65 + k];
        acc[0][0] = fmaf(rv0, w.x, acc[0][0]); acc[0][1] = fmaf(rv0, w.y, acc[0][1]);
        acc[0][2] = fmaf(rv0, w.z, acc[0][2]); acc[0][3] = fmaf(rv0, w.w, acc[0][3]);
        acc[1][0] = fmaf(rv1, w.x, acc[1][0]); acc[1][1] = fmaf(rv1, w.y, acc[1][1]);
        acc[1][2] = fmaf(rv1, w.z, acc[1][2]); acc[1][3] = fmaf(rv1, w.w, acc[1][3]);
        acc[2][0] = fmaf(rv2, w.x, acc[2][0]); acc[2][1] = fmaf(rv2, w.y, acc[2][1]);
        acc[2][2] = fmaf(rv2, w.z, acc[2][2]); acc[2][3] = fmaf(rv2, w.w, acc[2][3]);
        acc[3][0] = fmaf(rv3, w.x, acc[3][0]); acc[3][1] = fmaf(rv3, w.y, acc[3][1]);
        acc[3][2] = fmaf(rv3, w.z, acc[3][2]); acc[3][3] = fmaf(rv3, w.w, acc[3][3]);
    }
#pragma unroll
    for (int r = 0; r < 4; ++r) {
        float dv = sdinv[r0 + r];
        union { __half2 h[2]; uint2 u; } pk;
        pk.h[0] = __floats2half2_rn(fmaxf(acc[r][0], 0.0f) * dv, fmaxf(acc[r][1], 0.0f) * dv);
        pk.h[1] = __floats2half2_rn(fmaxf(acc[r][2], 0.0f) * dv, fmaxf(acc[r][3], 0.0f) * dv);
        h16[(size_t)(base + r0 + r) * 32 + jg] = pk.u;
    }
}

// ---------------- mu/logstd = aggH @ [Wmu|Wls] + b, fp16 aggH in, 4x4 tile ----------------
// Also emits fp16 copy of z (=mu) for the decoder.
__global__ __launch_bounds__(256) void k_out(const uint4* __restrict__ aggH16,
                                             const float4* __restrict__ Wmu4, // [128][16] f4
                                             const float* __restrict__ bmu,
                                             const float4* __restrict__ Wls4, // [128][16] f4
                                             const float* __restrict__ bls,
                                             float* __restrict__ out,
                                             uint2* __restrict__ z16) {
    __shared__ float4 w4[64 * 32];     // w4[kk*32+jj] = W[kh*64+kk][4jj..4jj+3] combined
    __shared__ float rows[32 * 129];   // padded, full 128 feats
    int t = threadIdx.x;
    int base = blockIdx.x * 32;
#pragma unroll
    for (int i = 0; i < 2; ++i) {
        int idx = t + i * 256;          // 512 uint4 total = 32 rows x 16
        int r = idx >> 4, c = idx & 15;
        float f[8]; h8_to_f(aggH16[(size_t)(base + r) * 16 + c], f);
#pragma unroll
        for (int kk = 0; kk < 8; ++kk) rows[r * 129 + c * 8 + kk] = f[kk];
    }
    int rg = t >> 5, jg = t & 31;
    int r0 = rg * 4;
    float4 bias = (jg < 16) ? ((const float4*)bmu)[jg] : ((const float4*)bls)[jg - 16];
    float acc[4][4];
#pragma unroll
    for (int r = 0; r < 4; ++r) {
        acc[r][0] = bias.x; acc[r][1] = bias.y; acc[r][2] = bias.z; acc[r][3] = bias.w;
    }
    for (int kh = 0; kh < 2; ++kh) {
        if (kh) __syncthreads();      // all waves done reading previous w4
#pragma unroll
        for (int i = 0; i < 8; ++i) {
            int idx = t + i * 256;
            int jj = idx & 31, kk = idx >> 5;
            int k = kh * 64 + kk;
            w4[idx] = (jj < 16) ? Wmu4[k * 16 + jj] : Wls4[k * 16 + (jj - 16)];
        }
        __syncthreads();
#pragma unroll 8
        for (int kk = 0; kk < 64; ++kk) {
            int k = kh * 64 + kk;
            float4 w = w4[kk * 32 + jg];
            float rv0 = rows[(r0 + 0) * 129 + k];
            float rv1 = rows[(r0 + 1) * 129 + k];
            float rv2 = rows[(r0 + 2) * 129 + k];
            float rv3 = rows[(r0 + 3) * 129 + k];
            acc[0][0] = fmaf(rv0, w.x, acc[0][0]); acc[0][1] = fmaf(rv0, w.y, acc[0][1]);
            acc[0][2] = fmaf(rv0, w.z, acc[0][2]); acc[0][3] = fmaf(rv0, w.w, acc[0][3]);
            acc[1][0] = fmaf(rv1, w.x, acc[1][0]); acc[1][1] = fmaf(rv1, w.y, acc[1][1]);
            acc[1][2] = fmaf(rv1, w.z, acc[1][2]); acc[1][3] = fmaf(rv1, w.w, acc[1][3]);
            acc[2][0] = fmaf(rv2, w.x, acc[2][0]); acc[2][1] = fmaf(rv2, w.y, acc[2][1]);
            acc[2][2] = fmaf(rv2, w.z, acc[2][2]); acc[2][3] = fmaf(rv2, w.w, acc[2][3]);
            acc[3][0] = fmaf(rv3, w.x, acc[3][0]); acc[3][1] = fmaf(rv3, w.y, acc[3][1]);
            acc[3][2] = fmaf(rv3, w.z, acc[3][2]); acc[3][3] = fmaf(rv3, w.w, acc[3][3]);
        }
    }
    float4* out4 = (float4*)out;
    if (jg < 16) {
#pragma unroll
        for (int r = 0; r < 4; ++r) {
            out4[(size_t)(base + r0 + r) * 16 + jg] =
                make_float4(acc[r][0], acc[r][1], acc[r][2], acc[r][3]);
            union { __half2 h[2]; uint2 u; } pk;
            pk.h[0] = __floats2half2_rn(acc[r][0], acc[r][1]);
            pk.h[1] = __floats2half2_rn(acc[r][2], acc[r][3]);
            z16[(size_t)(base + r0 + r) * 16 + jg] = pk.u;
        }
    } else {
#pragma unroll
        for (int r = 0; r < 4; ++r) {
            float4 o = make_float4(fminf(acc[r][0], 10.0f), fminf(acc[r][1], 10.0f),
                                   fminf(acc[r][2], 10.0f), fminf(acc[r][3], 10.0f));
            out4[(size_t)NN * 16 + (size_t)(base + r0 + r) * 16 + (jg - 16)] = o;
        }
    }
}

// ---------------- decoder loss: fp16 z, 4 edges per 16-lane group ----------------
__global__ __launch_bounds__(256) void k_loss(const int* __restrict__ pos,
                                              const int* __restrict__ neg,
                                              const uint2* __restrict__ z16,
                                              float* __restrict__ accum) {
    int t = blockIdx.x * blockDim.x + threadIdx.x;
    int grp = t >> 4, q = t & 15;
    int e0 = grp * 4;                          // 4 consecutive ids in [0, 2*NP)
    bool isNeg = e0 >= NP;                     // uniform within group (NP % 4 == 0)
    const int* idx = isNeg ? neg : pos;
    int eb = isNeg ? e0 - NP : e0;
    int a0 = idx[eb + 0], b0 = idx[NP + eb + 0];
    int a1 = idx[eb + 1], b1 = idx[NP + eb + 1];
    int a2 = idx[eb + 2], b2 = idx[NP + eb + 2];
    int a3 = idx[eb + 3], b3 = idx[NP + eb + 3];
    uint2 ua0 = z16[(size_t)a0 * 16 + q], ub0 = z16[(size_t)b0 * 16 + q];
    uint2 ua1 = z16[(size_t)a1 * 16 + q], ub1 = z16[(size_t)b1 * 16 + q];
    uint2 ua2 = z16[(size_t)a2 * 16 + q], ub2 = z16[(size_t)b2 * 16 + q];
    uint2 ua3 = z16[(size_t)a3 * 16 + q], ub3 = z16[(size_t)b3 * 16 + q];
    float d0 = dot4h(ua0, ub0);
    float d1 = dot4h(ua1, ub1);
    float d2 = dot4h(ua2, ub2);
    float d3 = dot4h(ua3, ub3);
#pragma unroll
    for (int off = 1; off < 16; off <<= 1) {
        d0 += __shfl_xor(d0, off);
        d1 += __shfl_xor(d1, off);
        d2 += __shfl_xor(d2, off);
        d3 += __shfl_xor(d3, off);
    }
    __shared__ float bsum[2];
    if (threadIdx.x < 2) bsum[threadIdx.x] = 0.0f;
    __syncthreads();
    if (q == 0) {
        float term;
        if (isNeg) {
            term = logf(1.0f - 1.0f / (1.0f + expf(-d0)) + 1e-15f)
                 + logf(1.0f - 1.0f / (1.0f + expf(-d1)) + 1e-15f)
                 + logf(1.0f - 1.0f / (1.0f + expf(-d2)) + 1e-15f)
                 + logf(1.0f - 1.0f / (1.0f + expf(-d3)) + 1e-15f);
        } else {
            term = logf(1.0f / (1.0f + expf(-d0)) + 1e-15f)
                 + logf(1.0f / (1.0f + expf(-d1)) + 1e-15f)
                 + logf(1.0f / (1.0f + expf(-d2)) + 1e-15f)
                 + logf(1.0f / (1.0f + expf(-d3)) + 1e-15f);
        }
        atomicAdd(&bsum[isNeg ? 1 : 0], term);
    }
    __syncthreads();
    if (threadIdx.x < 2) atomicAdd(&accum[threadIdx.x], bsum[threadIdx.x]);
}

__global__ void k_fin(const float* __restrict__ accum, float* __restrict__ out) {
    out[(size_t)NN * 128] = -(accum[0] + accum[1]) * (1.0f / (float)NP);
}

extern "C" void kernel_launch(void* const* d_in, const int* in_sizes, int n_in,
                              void* d_out, int out_size, void* d_ws, size_t ws_size,
                              hipStream_t stream) {
    const float* emb = (const float*)d_in[0];
    const int*   ei  = (const int*)d_in[1];
    const float* W1  = (const float*)d_in[2];
    const float* b1  = (const float*)d_in[3];
    const float* Wmu = (const float*)d_in[4];
    const float* bmu = (const float*)d_in[5];
    const float* Wls = (const float*)d_in[6];
    const float* bls = (const float*)d_in[7];
    const int*   pos = (const int*)d_in[8];
    const int*   neg = (const int*)d_in[9];
    float* out = (float*)d_out;

    char* ws = (char*)d_ws;
    // small buffers
    float* dinv   = (float*)(ws);                        // 400 KB  (written by k_binB)
    int*   rowptr = (int*)  (ws + (512 << 10));          // 400 KB + 4 (written by k_binB)
    int*   bcnt   = (int*)  (ws + (1024 << 10));         // 1 KB
    int*   bbase  = (int*)  (ws + (1028 << 10));         // 1 KB + 4
    int*   gcnt   = (int*)  (ws + (1032 << 10));         // 1 KB
    float* accum  = (float*)(ws + (1040 << 10));         // 8 B
    // big buffers. Liveness:
    //   edges  [k_binA .. k_aggH]                          6.4 MB (4B records)
    //   h16    [k_h .. k_aggH]                             25.6 MB
    //   z16    [k_out .. k_loss]   ALIASES h16 (dead)      12.8 MB
    //   emb16  [k_cvt .. k_aggE]                           12.8 MB
    //   aggH16 [k_aggH .. k_out]   ALIASES emb16 (dead)    25.6 MB
    //   aggE   [k_aggE .. k_h]     staged in d_out         25.6 MB
    const size_t OFF_EDGES = (2048 << 10);                       // +6.4 MB
    const size_t OFF_H16   = OFF_EDGES + (size_t)NE * 4;         // +25.6 MB
    const size_t OFF_E16   = OFF_H16 + (size_t)NN * 128 * 2;     // +25.6 MB (aggH16 extent)
    int*   edges  = (int*)(ws + OFF_EDGES);
    uint2* h16    = (uint2*)(ws + OFF_H16);
    uint2* z16    = (uint2*)(ws + OFF_H16);              // h16 dead by k_out
    uint4* emb16  = (uint4*)(ws + OFF_E16);
    uint4* aggH16 = (uint4*)(ws + OFF_E16);              // emb16 dead by k_aggH
    float* aggE   = out;                                 // 25.6 MB staged in d_out

    hipMemsetAsync(bcnt, 0, NBK * sizeof(int), stream);
    hipMemsetAsync(accum, 0, 2 * sizeof(float), stream);

    k_hist <<<NE / K_A, 256, 0, stream>>>(ei, bcnt);
    k_bscan<<<1, 256, 0, stream>>>(bcnt, bbase, gcnt);
    k_binA <<<NE / K_A, 256, 0, stream>>>(ei, gcnt, edges);
    k_binB <<<NBK, 256, 0, stream>>>(bbase, edges, rowptr, dinv);

    k_cvt  <<<(NN * 8 + 255) / 256, 256, 0, stream>>>((const float4*)emb, dinv, emb16);

    k_aggE<<<(NN * 8) / 256, 256, 0, stream>>>(emb16, dinv, rowptr, edges, (float4*)aggE);
    k_h<<<NN / 32, 256, 0, stream>>>(aggE, (const float4*)W1, b1, dinv, h16);

    k_aggH<<<(NN * 16) / 256, 256, 0, stream>>>((const uint4*)h16, dinv, rowptr, edges, aggH16);
    k_out<<<NN / 32, 256, 0, stream>>>(aggH16, (const float4*)Wmu, bmu,
                                       (const float4*)Wls, bls, out, z16);

    k_loss<<<(2 * NP * 16) / (256 * 4), 256, 0, stream>>>(pos, neg, z16, accum);
    k_fin<<<1, 1, 0, stream>>>(accum, out);
}